// Round 12
// baseline (142.184 us; speedup 1.0000x reference)
//
#include <hip/hip_runtime.h>
#include <hip/hip_bf16.h>
#include <math.h>

typedef __bf16 bf16_t;
typedef bf16_t bf16x4 __attribute__((ext_vector_type(4)));
typedef bf16_t bf16x8 __attribute__((ext_vector_type(8)));
typedef float f32x4 __attribute__((ext_vector_type(4)));

#define SEQ 2048
#define BATCH 2
#define NHEAD 16
#define DK 64
#define DMODEL 1024

#define GLOAD16(gsrc, ldst)                                                        \
    __builtin_amdgcn_global_load_lds(                                              \
        (const __attribute__((address_space(1))) void*)(gsrc),                     \
        (__attribute__((address_space(3))) void*)(ldst), 16, 0, 0)

__device__ __forceinline__ float exp2_hw(float x) {
#if __has_builtin(__builtin_amdgcn_exp2f)
    return __builtin_amdgcn_exp2f(x);
#else
    float r; asm("v_exp_f32 %0, %1" : "=v"(r) : "v"(x)); return r;
#endif
}

// ---------------- fused prep: cvt x -> bf16 | transpose 4x W -> bf16 | rope table ----
__global__ __launch_bounds__(256)
void prep_kernel(const float* __restrict__ x, bf16_t* __restrict__ y,
                 const float* __restrict__ W0, const float* __restrict__ W1,
                 const float* __restrict__ W2, const float* __restrict__ W3,
                 bf16_t* __restrict__ Wt, float2* __restrict__ cs) {
    __shared__ float t[32][33];
    const int id = blockIdx.x, tid = threadIdx.x;
    if (id < 4096) {                               // cvt x (4096 blocks)
        int i = (id * 256 + tid) * 4;
        float4 v = *reinterpret_cast<const float4*>(x + i);
        bf16x4 o = { (bf16_t)v.x, (bf16_t)v.y, (bf16_t)v.z, (bf16_t)v.w };
        *reinterpret_cast<bf16x4*>(y + i) = o;
    } else if (id < 8192) {                        // transpose W (4096 blocks)
        const int id2 = id - 4096;
        const int z = id2 >> 10, rem = id2 & 1023;
        const int n0 = (rem & 31) * 32, k0 = ((rem >> 5) & 31) * 32;
        const int tx = tid & 31, ty = tid >> 5;    // 32 x 8
        const float* W = (z == 0) ? W0 : (z == 1) ? W1 : (z == 2) ? W2 : W3;
        bf16_t* out = Wt + ((size_t)z << 20);
#pragma unroll
        for (int i = 0; i < 32; i += 8)
            t[ty + i][tx] = W[(size_t)(k0 + ty + i) * DMODEL + n0 + tx];
        __syncthreads();
#pragma unroll
        for (int i = 0; i < 32; i += 8)
            out[(size_t)(n0 + ty + i) * DMODEL + k0 + tx] = (bf16_t)t[tx][ty + i];
    } else {                                       // rope table (256 blocks)
        int idx = (id - 8192) * 256 + tid;         // SEQ*32
        int j = idx & 31, s = idx >> 5;
        float inv = powf(10000.0f, -(float)j / 32.0f);
        float ang = (float)s * inv;
        cs[idx] = make_float2(cosf(ang), sinf(ang));
    }
}

// ---------------- GEMM core: 128 x (NF*32) tile, BK=32, 3-deep prefetch ----------------
template<int NF>
__device__ __forceinline__ void gemm_core(const bf16_t* __restrict__ A,
                                          const bf16_t* __restrict__ Bt,
                                          int m0, int n0,
                                          bf16_t* As, bf16_t* Bs,
                                          f32x4 (&acc)[4][NF]) {
    const int tid = threadIdx.x, lane = tid & 63, wid = tid >> 6;
    const int wr = wid >> 1, wc = wid & 1;
    const int lm = lane & 15, lq = lane >> 4;
    constexpr int BROWS = NF * 32;
    constexpr int NT = DMODEL / 32;

    const int r_in = lane >> 2;                                  // 0..15
    const int csw  = (((lane & 3) ^ ((lane >> 3) & 3)) << 3);    // src col (elems)
    const bf16_t* Ag = A  + (size_t)(m0 + 32 * wid + r_in) * DMODEL + csw;
    const bf16_t* Bg = Bt + (size_t)(n0 + (NF * 8) * wid + r_in) * DMODEL + csw;
    const int cswr = ((lq ^ ((lm >> 1) & 3)) << 4);

    auto stage = [&](int t, int buf) {
        const int k0 = t * 32;
        bf16_t* a = As + buf * (128 * 32) + 32 * wid * 32;
        bf16_t* b = Bs + buf * (BROWS * 32) + (NF * 8) * wid * 32;
        GLOAD16(Ag + k0,               a);
        GLOAD16(Ag + 16 * DMODEL + k0, a + 16 * 32);
        GLOAD16(Bg + k0,               b);
        if constexpr (NF == 4) GLOAD16(Bg + 16 * DMODEL + k0, b + 16 * 32);
    };

    stage(0, 0);
    stage(1, 1);
    int cb = 0;
    for (int t = 0; t < NT; ++t) {
        if (t + 2 < NT) {
            int sb = cb + 2; if (sb >= 3) sb -= 3;
            stage(t + 2, sb);
            if constexpr (NF == 4) asm volatile("s_waitcnt vmcnt(8)" ::: "memory");
            else                   asm volatile("s_waitcnt vmcnt(6)" ::: "memory");
        } else if (t + 1 < NT) {
            if constexpr (NF == 4) asm volatile("s_waitcnt vmcnt(4)" ::: "memory");
            else                   asm volatile("s_waitcnt vmcnt(3)" ::: "memory");
        } else {
            asm volatile("s_waitcnt vmcnt(0)" ::: "memory");
        }
        __builtin_amdgcn_s_barrier();

        const char* pAs = (const char*)(As + cb * (128 * 32));
        const char* pBs = (const char*)(Bs + cb * (BROWS * 32));
        bf16x8 af[4], bfr[NF];
#pragma unroll
        for (int mf = 0; mf < 4; ++mf)
            af[mf] = *reinterpret_cast<const bf16x8*>(pAs + (wr * 64 + mf * 16 + lm) * 64 + cswr);
#pragma unroll
        for (int nf = 0; nf < NF; ++nf)
            bfr[nf] = *reinterpret_cast<const bf16x8*>(pBs + (wc * (NF * 16) + nf * 16 + lm) * 64 + cswr);
#pragma unroll
        for (int mf = 0; mf < 4; ++mf)
#pragma unroll
            for (int nf = 0; nf < NF; ++nf)
                acc[mf][nf] = __builtin_amdgcn_mfma_f32_16x16x32_bf16(af[mf], bfr[nf], acc[mf][nf], 0, 0, 0);

        asm volatile("" ::: "memory");
        __builtin_amdgcn_s_barrier();
        if (++cb == 3) cb = 0;
    }
}

// ---------------- fused QKV projections: 768 blocks (XCD-swizzled) ----------------
__global__ __launch_bounds__(256)
void gemm_qkv_kernel(const bf16_t* __restrict__ xb, const bf16_t* __restrict__ wtqk,
                     const bf16_t* __restrict__ wtv,
                     const float* __restrict__ bq, const float* __restrict__ bk,
                     const float* __restrict__ bv,
                     bf16_t* __restrict__ qb, bf16_t* __restrict__ kb,
                     bf16_t* __restrict__ vtb, const float2* __restrict__ cs) {
    __shared__ bf16_t As[3 * 128 * 32];
    __shared__ bf16_t Bs[3 * 128 * 32];
    const int tid = threadIdx.x, lane = tid & 63, wid = tid >> 6;
    const int wr = wid >> 1, wc = wid & 1;
    const int lm = lane & 15, lq = lane >> 4;
    const int orig = blockIdx.x;
    const int id = (orig & 7) * 96 + (orig >> 3);   // bijective XCD swizzle (768 = 8*96)
    f32x4 acc[4][4] = {};

    if (id < 512) {
        const int m0 = (id >> 4) * 128, n0 = (id & 15) * 128;
        gemm_core<4>(xb, wtqk, m0, n0, As, Bs, acc);
        const bool is_k = (n0 >= 1024);
        const float* bs = is_k ? bk : bq;
        bf16_t* C = is_k ? kb : qb;
        const int cb = (is_k ? n0 - 1024 : n0) + wc * 64;
        const float b0 = bs[cb + lm],      b1 = bs[cb + 16 + lm];
        const float b2 = bs[cb + 32 + lm], b3 = bs[cb + 48 + lm];
#pragma unroll
        for (int mf = 0; mf < 4; ++mf)
#pragma unroll
            for (int i = 0; i < 4; ++i) {
                const int row = m0 + wr * 64 + mf * 16 + lq * 4 + i;
                const int s = row & (SEQ - 1);
                const float2 cs0 = cs[s * 32 + lm];
                const float2 cs1 = cs[s * 32 + 16 + lm];
                const float a0 = acc[mf][0][i] + b0, a1 = acc[mf][1][i] + b1;
                const float a2 = acc[mf][2][i] + b2, a3 = acc[mf][3][i] + b3;
                bf16_t* p = C + (size_t)row * DMODEL + cb;
                p[lm]      = (bf16_t)(a0 * cs0.x - a2 * cs0.y);
                p[16 + lm] = (bf16_t)(a1 * cs1.x - a3 * cs1.y);
                p[32 + lm] = (bf16_t)(a2 * cs0.x + a0 * cs0.y);
                p[48 + lm] = (bf16_t)(a3 * cs1.x + a1 * cs1.y);
            }
    } else {
        const int id2 = id - 512;
        const int m0 = (id2 & 7) * 128, n0 = (id2 >> 3) * 128;
        gemm_core<4>(wtv, xb, m0, n0, As, Bs, acc);
#pragma unroll
        for (int mf = 0; mf < 4; ++mf)
#pragma unroll
            for (int i = 0; i < 4; ++i) {
                const int row = m0 + wr * 64 + mf * 16 + lq * 4 + i;
                const float brow = bv[row];
#pragma unroll
                for (int nf = 0; nf < 4; ++nf) {
                    const int col = n0 + wc * 64 + nf * 16 + lm;
                    vtb[(size_t)row * 4096 + col] = (bf16_t)(acc[mf][nf][i] + brow);
                }
            }
    }
}

// ---------------- output projection: 128x128 tile, 256 blocks (XCD-swizzled) ----------
__global__ __launch_bounds__(256)
void gemm_out_kernel(const bf16_t* __restrict__ A, const bf16_t* __restrict__ Bt,
                     const float* __restrict__ bias, float* __restrict__ C) {
    __shared__ bf16_t As[3 * 128 * 32];
    __shared__ bf16_t Bs[3 * 128 * 32];
    const int tid = threadIdx.x, lane = tid & 63, wid = tid >> 6;
    const int wr = wid >> 1, wc = wid & 1;
    const int lm = lane & 15, lq = lane >> 4;
    const int orig = blockIdx.x;
    const int id = (orig & 7) * 32 + (orig >> 3);   // bijective XCD swizzle (256 = 8*32)
    const int m0 = (id >> 3) * 128, n0 = (id & 7) * 128;
    f32x4 acc[4][4] = {};
    gemm_core<4>(A, Bt, m0, n0, As, Bs, acc);
#pragma unroll
    for (int nf = 0; nf < 4; ++nf) {
        const int col = n0 + wc * 64 + nf * 16 + lm;
        const float bcol = bias[col];
#pragma unroll
        for (int mf = 0; mf < 4; ++mf)
#pragma unroll
            for (int i = 0; i < 4; ++i) {
                const int row = m0 + wr * 64 + mf * 16 + lq * 4 + i;
                C[(size_t)row * DMODEL + col] = acc[mf][nf][i] + bcol;
            }
    }
}

// ---------------- flash attention: 64 q-rows/wave (4 Q-sets), 4 waves, 256 blocks ------
// K/V LDS reads amortized over 4 Q-sets (halved bytes/FLOP). In-register P via
// sigma-permuted K staging; denominator on VALU (fused with exp2); static max in
// acc-init. 4 LDS buffers, 2-ahead staging, counted vmcnt(8), 1 barrier/iter.
__global__ __launch_bounds__(256)
void attn_kernel(const bf16_t* __restrict__ q, const bf16_t* __restrict__ k,
                 const bf16_t* __restrict__ vt, bf16_t* __restrict__ attnout) {
    const int tid = threadIdx.x, lane = tid & 63, wid = tid >> 6;
    const int lm = lane & 15, lq = lane >> 4;
    // XCD-locality decode: xcd = bid&7 owns bh in [4*xcd, 4*xcd+4)
    const int bid = blockIdx.x;
    const int xcd = bid & 7, idx = bid >> 3;
    const int bh = xcd * 4 + (idx & 3), qblk = idx >> 2;   // qblk 0..7
    const int b = bh >> 4, h = bh & 15;
    const int qrow0 = qblk * 256 + wid * 64;
    const float MS = 20.0f;
    constexpr int NT = SEQ / 64;     // 32 KV tiles

    __shared__ bf16_t Ks[4][64][64];
    __shared__ bf16_t Vs[4][64][64];

    // Q fragments (B-operand), 4 sets of 16 rows, pre-scaled by (1/sqrt(64))*log2(e)
    const bf16_t* qp = q + ((size_t)(b * SEQ + qrow0 + lm) * NHEAD + h) * DK + lq * 8;
    bf16x8 aq[4][2];
#pragma unroll
    for (int s = 0; s < 4; ++s) {
        aq[s][0] = *reinterpret_cast<const bf16x8*>(qp + (size_t)(16 * s) * NHEAD * DK);
        aq[s][1] = *reinterpret_cast<const bf16x8*>(qp + (size_t)(16 * s) * NHEAD * DK + 32);
#pragma unroll
        for (int j = 0; j < 8; ++j) {
            aq[s][0][j] = (bf16_t)((float)aq[s][0][j] * 0.18033688f);
            aq[s][1][j] = (bf16_t)((float)aq[s][1][j] * 0.18033688f);
        }
    }
    const f32x4 cinit = { -MS, -MS, -MS, -MS };

    // staging (sigma row permutation folded into K source row); wave stages 16 LDS rows
    const int rr = lane >> 3;                               // 0..7
    const int scol = (((lane & 7) ^ rr) << 3);              // swizzled src col (elems)
    const int r0 = 16 * wid + rr, r1 = r0 + 8;
    const int sg0 = (r0 & 32) | (((r0 >> 2) & 3) * 8 + ((r0 >> 4) & 1) * 4 + (r0 & 3));
    const int sg1 = (r1 & 32) | (((r1 >> 2) & 3) * 8 + ((r1 >> 4) & 1) * 4 + (r1 & 3));
    const size_t kstep = (size_t)NHEAD * DK;
    const bf16_t* kg0 = k + ((size_t)(b * SEQ + sg0) * NHEAD + h) * DK + scol;
    const bf16_t* kg1 = k + ((size_t)(b * SEQ + sg1) * NHEAD + h) * DK + scol;
    const bf16_t* vg0 = vt + ((size_t)(h * DK + r0)) * 4096 + (size_t)b * SEQ + scol;
    const bf16_t* vg1 = vt + ((size_t)(h * DK + r1)) * 4096 + (size_t)b * SEQ + scol;
    const char* ksb = (const char*)Ks;
    const char* vsb = (const char*)Vs;
    const int c0 = (lq << 4) ^ ((lm & 7) << 4);
    const int rowb = lm * 128;

    f32x4 O[4][4] = {};
    float rs[4] = {};

    auto stage = [&](int buf, int kb) {
        GLOAD16(kg0 + (size_t)kb * kstep, &Ks[buf][16 * wid][0]);
        GLOAD16(kg1 + (size_t)kb * kstep, &Ks[buf][16 * wid + 8][0]);
        GLOAD16(vg0 + kb,                 &Vs[buf][16 * wid][0]);
        GLOAD16(vg1 + kb,                 &Vs[buf][16 * wid + 8][0]);
    };

    stage(0, 0);
    stage(1, 64);

    for (int t = 0; t < NT; ++t) {
        if (t + 2 < NT) {
            stage((t + 2) & 3, (t + 2) * 64);
            asm volatile("s_waitcnt vmcnt(8)" ::: "memory");
        } else if (t + 1 < NT) {
            asm volatile("s_waitcnt vmcnt(4)" ::: "memory");
        } else {
            asm volatile("s_waitcnt vmcnt(0)" ::: "memory");
        }
        __builtin_amdgcn_s_barrier();
        asm volatile("" ::: "memory");

        const char* kt  = ksb + (t & 3) * 8192;
        const char* vtl = vsb + (t & 3) * 8192;

        bf16x8 a0[4], a1[4], v0[4], v1[4];
#pragma unroll
        for (int u = 0; u < 4; ++u) {
            a0[u] = *reinterpret_cast<const bf16x8*>(kt + u * 2048 + rowb + c0);
            a1[u] = *reinterpret_cast<const bf16x8*>(kt + u * 2048 + rowb + (c0 ^ 64));
            v0[u] = *reinterpret_cast<const bf16x8*>(vtl + u * 2048 + rowb + c0);
            v1[u] = *reinterpret_cast<const bf16x8*>(vtl + u * 2048 + rowb + (c0 ^ 64));
        }

#pragma unroll
        for (int s = 0; s < 4; ++s) {
            f32x4 st[4];
            __builtin_amdgcn_s_setprio(1);
#pragma unroll
            for (int u = 0; u < 4; ++u) {
                f32x4 x = __builtin_amdgcn_mfma_f32_16x16x32_bf16(a0[u], aq[s][0], cinit, 0, 0, 0);
                st[u] = __builtin_amdgcn_mfma_f32_16x16x32_bf16(a1[u], aq[s][1], x, 0, 0, 0);
            }
            __builtin_amdgcn_s_setprio(0);

            bf16x8 pa0, pa1;
            float acc = 0.f;
#pragma unroll
            for (int u = 0; u < 2; ++u)
#pragma unroll
                for (int i = 0; i < 4; ++i) {
                    const float e0 = exp2_hw(st[u][i]);
                    const float e1 = exp2_hw(st[u + 2][i]);
                    acc += e0 + e1;
                    pa0[4 * u + i] = (bf16_t)e0;
                    pa1[4 * u + i] = (bf16_t)e1;
                }
            rs[s] += acc;

            __builtin_amdgcn_s_setprio(1);
#pragma unroll
            for (int nf = 0; nf < 4; ++nf) {
                f32x4 o = O[s][nf];
                o = __builtin_amdgcn_mfma_f32_16x16x32_bf16(v0[nf], pa0, o, 0, 0, 0);
                o = __builtin_amdgcn_mfma_f32_16x16x32_bf16(v1[nf], pa1, o, 0, 0, 0);
                O[s][nf] = o;
            }
            __builtin_amdgcn_s_setprio(0);
        }

        asm volatile("" ::: "memory");
        __builtin_amdgcn_s_barrier();
    }

#pragma unroll
    for (int s = 0; s < 4; ++s) {
        float rt = rs[s];
        rt += __shfl_xor(rt, 16, 64);
        rt += __shfl_xor(rt, 32, 64);
        const float inv = 1.0f / rt;
        bf16_t* ob = attnout + ((size_t)(b * SEQ + qrow0 + s * 16 + lm) * NHEAD + h) * DK;
#pragma unroll
        for (int nf = 0; nf < 4; ++nf) {
            bf16x4 c = { (bf16_t)(O[s][nf][0] * inv), (bf16_t)(O[s][nf][1] * inv),
                         (bf16_t)(O[s][nf][2] * inv), (bf16_t)(O[s][nf][3] * inv) };
            *reinterpret_cast<bf16x4*>(ob + nf * 16 + lq * 4) = c;
        }
    }
}

extern "C" void kernel_launch(void* const* d_in, const int* in_sizes, int n_in,
                              void* d_out, int out_size, void* d_ws, size_t ws_size,
                              hipStream_t stream) {
    const float* x  = (const float*)d_in[0];
    const float* Wq = (const float*)d_in[1];
    const float* bq = (const float*)d_in[2];
    const float* Wk = (const float*)d_in[3];
    const float* bk = (const float*)d_in[4];
    const float* Wv = (const float*)d_in[5];
    const float* bv = (const float*)d_in[6];
    const float* Wo = (const float*)d_in[7];
    const float* bo = (const float*)d_in[8];
    float* out = (float*)d_out;

    char* ws = (char*)d_ws;
    bf16_t* xb  = (bf16_t*)(ws);                       // 8MB (x bf16; reused as attn-out)
    bf16_t* wtq = (bf16_t*)(ws + ((size_t)8  << 20));  // 4 x 2MB transposed weights (q,k,v,o)
    bf16_t* wtv = wtq + (2 << 20);
    bf16_t* wto = wtq + (3 << 20);
    bf16_t* qb  = (bf16_t*)(ws + ((size_t)16 << 20));  // 8MB
    bf16_t* kb  = (bf16_t*)(ws + ((size_t)24 << 20));  // 8MB
    bf16_t* vtb = (bf16_t*)(ws + ((size_t)32 << 20));  // 8MB, [1024][4096]
    float2* csT = (float2*)(ws + ((size_t)40 << 20));  // 512KB
    bf16_t* aob = xb;

    prep_kernel<<<8448, 256, 0, stream>>>(x, xb, Wq, Wk, Wv, Wo, wtq, csT);
    gemm_qkv_kernel<<<768, 256, 0, stream>>>(xb, wtq, wtv, bq, bk, bv, qb, kb, vtb, csT);
    attn_kernel<<<256, 256, 0, stream>>>(qb, kb, vtb, aob);
    gemm_out_kernel<<<256, 256, 0, stream>>>(aob, wto, bo, out);
}

// Round 13
// 130.876 us; speedup vs baseline: 1.0864x; 1.0864x over previous
//
#include <hip/hip_runtime.h>
#include <hip/hip_bf16.h>
#include <math.h>

typedef __bf16 bf16_t;
typedef bf16_t bf16x4 __attribute__((ext_vector_type(4)));
typedef bf16_t bf16x8 __attribute__((ext_vector_type(8)));
typedef float f32x4 __attribute__((ext_vector_type(4)));

#define SEQ 2048
#define BATCH 2
#define NHEAD 16
#define DK 64
#define DMODEL 1024

#define GLOAD16(gsrc, ldst)                                                        \
    __builtin_amdgcn_global_load_lds(                                              \
        (const __attribute__((address_space(1))) void*)(gsrc),                     \
        (__attribute__((address_space(3))) void*)(ldst), 16, 0, 0)

#define MFMA16(a, b, c) __builtin_amdgcn_mfma_f32_16x16x32_bf16((a), (b), (c), 0, 0, 0)

__device__ __forceinline__ float exp2_hw(float x) {
#if __has_builtin(__builtin_amdgcn_exp2f)
    return __builtin_amdgcn_exp2f(x);
#else
    float r; asm("v_exp_f32 %0, %1" : "=v"(r) : "v"(x)); return r;
#endif
}

// ---------------- fused prep: cvt x -> bf16 | transpose 4x W -> bf16 | rope table ----
__global__ __launch_bounds__(256)
void prep_kernel(const float* __restrict__ x, bf16_t* __restrict__ y,
                 const float* __restrict__ W0, const float* __restrict__ W1,
                 const float* __restrict__ W2, const float* __restrict__ W3,
                 bf16_t* __restrict__ Wt, float2* __restrict__ cs) {
    __shared__ float t[32][33];
    const int id = blockIdx.x, tid = threadIdx.x;
    if (id < 4096) {                               // cvt x (4096 blocks)
        int i = (id * 256 + tid) * 4;
        float4 v = *reinterpret_cast<const float4*>(x + i);
        bf16x4 o = { (bf16_t)v.x, (bf16_t)v.y, (bf16_t)v.z, (bf16_t)v.w };
        *reinterpret_cast<bf16x4*>(y + i) = o;
    } else if (id < 8192) {                        // transpose W (4096 blocks)
        const int id2 = id - 4096;
        const int z = id2 >> 10, rem = id2 & 1023;
        const int n0 = (rem & 31) * 32, k0 = ((rem >> 5) & 31) * 32;
        const int tx = tid & 31, ty = tid >> 5;    // 32 x 8
        const float* W = (z == 0) ? W0 : (z == 1) ? W1 : (z == 2) ? W2 : W3;
        bf16_t* out = Wt + ((size_t)z << 20);
#pragma unroll
        for (int i = 0; i < 32; i += 8)
            t[ty + i][tx] = W[(size_t)(k0 + ty + i) * DMODEL + n0 + tx];
        __syncthreads();
#pragma unroll
        for (int i = 0; i < 32; i += 8)
            out[(size_t)(n0 + ty + i) * DMODEL + k0 + tx] = (bf16_t)t[tx][ty + i];
    } else {                                       // rope table (256 blocks)
        int idx = (id - 8192) * 256 + tid;         // SEQ*32
        int j = idx & 31, s = idx >> 5;
        float inv = powf(10000.0f, -(float)j / 32.0f);
        float ang = (float)s * inv;
        cs[idx] = make_float2(cosf(ang), sinf(ang));
    }
}

// ---------------- QKV: 256^2 8-phase template (m201 port), 192 blocks x 512 thr -------
// BM=BN=256, BK=64, 8 waves (2M x 4N), wave output 128x64. LDS 128KB: 2 dbuf x
// 2 halves x [128][64] for A and B. Swizzle byte ^= ((row&7)<<4) BOTH sides:
// pre-swizzled global source (linear global_load_lds dst) + swizzled ds_read.
// Per phase: stage 1 half-tile of kt+1 | (p0: counted vmcnt(2)) | barrier |
// ds_read subtile | setprio(1) 16 MFMA setprio(0) | barrier. Never vmcnt(0) mid-loop.
// id<128: QK gemm (A=xb, B=wtq|wtk) with fused rope; id>=128: V gemm transposed.
__global__ __launch_bounds__(512)
void gemm_qkv8_kernel(const bf16_t* __restrict__ xb, const bf16_t* __restrict__ wtqk,
                      const bf16_t* __restrict__ wtv,
                      const float* __restrict__ bq, const float* __restrict__ bk,
                      const float* __restrict__ bv,
                      bf16_t* __restrict__ qb, bf16_t* __restrict__ kb,
                      bf16_t* __restrict__ vtb, const float2* __restrict__ cs) {
    __shared__ bf16_t As[2][2][128 * 64];
    __shared__ bf16_t Bs[2][2][128 * 64];
    const int tid = threadIdx.x, lane = tid & 63, wid = tid >> 6;
    const int wm = wid >> 2, wn = wid & 3;
    const int lm = lane & 15, lq = lane >> 4;
    const int orig = blockIdx.x;
    const int id = (orig & 7) * 24 + (orig >> 3);   // bijective XCD swizzle (192 = 8*24)
    const bool isV = (id >= 128);
    const int id2 = isV ? id - 128 : id;
    const int m0 = isV ? (id2 & 3) * 256 : (id2 >> 3) * 256;
    const int n0 = isV ? (id2 >> 2) * 256 : (id2 & 7) * 256;
    const bf16_t* Amat = isV ? wtv : xb;
    const bf16_t* Bmat = isV ? xb : wtqk;

    // staging: thread covers linear dst byte d = wid*1024 + lane*16 (+ j*8192);
    // source col pre-swizzled so content at phys p equals logical p ^ ((row&7)<<4)
    const int scol = (((lane & 7) ^ (lane >> 3)) << 3);   // elems
    const int srow = wid * 8 + (lane >> 3);               // row-in-half (+ j*64)

    auto stageH = [&](int idx, int kt) {   // idx: 0=A0 1=A1 2=B0 3=B1
        const int buf = kt & 1, h = idx & 1;
        const bf16_t* g; bf16_t* d;
        if (idx < 2) { g = Amat + (size_t)(m0 + h * 128 + srow) * DMODEL + kt * 64 + scol;
                       d = &As[buf][h][wid * 512]; }
        else         { g = Bmat + (size_t)(n0 + h * 128 + srow) * DMODEL + kt * 64 + scol;
                       d = &Bs[buf][h][wid * 512]; }
        GLOAD16(g, d);
        GLOAD16(g + (size_t)64 * DMODEL, d + 4096);
    };

    f32x4 acc[8][4] = {};
    const int rB = (wn & 1) * 64;
    const int xsw = (lm & 7) << 4;

    // prologue: stage all 4 half-tiles of K-tile 0
    stageH(0, 0); stageH(1, 0); stageH(2, 0); stageH(3, 0);

    constexpr int NT = DMODEL / 64;   // 16 K-tiles
    for (int kt = 0; kt < NT; ++kt) {
        const char* pA = (const char*)&As[kt & 1][wm][0];
        const char* pB = (const char*)&Bs[kt & 1][wn >> 1][0];
        bf16x8 bfr[4][2];
#pragma unroll
        for (int p = 0; p < 4; ++p) {
            if (kt + 1 < NT) stageH(p, kt + 1);
            if (p == 0) {
                if (kt + 1 < NT) asm volatile("s_waitcnt vmcnt(2)" ::: "memory");
                else             asm volatile("s_waitcnt vmcnt(0)" ::: "memory");
            }
            __builtin_amdgcn_s_barrier();
            asm volatile("" ::: "memory");

            if (p == 0) {
#pragma unroll
                for (int nf = 0; nf < 4; ++nf)
#pragma unroll
                    for (int kk = 0; kk < 2; ++kk)
                        bfr[nf][kk] = *reinterpret_cast<const bf16x8*>(
                            pB + (rB + nf * 16 + lm) * 128 + (((kk << 6) | (lq << 4)) ^ xsw));
            }
            bf16x8 af[2][2];
#pragma unroll
            for (int m = 0; m < 2; ++m)
#pragma unroll
                for (int kk = 0; kk < 2; ++kk)
                    af[m][kk] = *reinterpret_cast<const bf16x8*>(
                        pA + ((2 * p + m) * 16 + lm) * 128 + (((kk << 6) | (lq << 4)) ^ xsw));

            __builtin_amdgcn_s_setprio(1);
#pragma unroll
            for (int m = 0; m < 2; ++m)
#pragma unroll
                for (int nf = 0; nf < 4; ++nf) {
                    f32x4 o = acc[2 * p + m][nf];
                    o = MFMA16(af[m][0], bfr[nf][0], o);
                    o = MFMA16(af[m][1], bfr[nf][1], o);
                    acc[2 * p + m][nf] = o;
                }
            __builtin_amdgcn_s_setprio(0);
            asm volatile("" ::: "memory");
            __builtin_amdgcn_s_barrier();
        }
    }

    if (!isV) {   // QK epilogue: one 64-col head per wave column, rope fused
        const int cba = n0 + wn * 64;
        const bool is_k = (cba >= 1024);
        const float* bs = is_k ? bk : bq;
        bf16_t* C = is_k ? kb : qb;
        const int cb = is_k ? cba - 1024 : cba;
        const float b0 = bs[cb + lm],      b1 = bs[cb + 16 + lm];
        const float b2 = bs[cb + 32 + lm], b3 = bs[cb + 48 + lm];
#pragma unroll
        for (int mf = 0; mf < 8; ++mf)
#pragma unroll
            for (int i = 0; i < 4; ++i) {
                const int row = m0 + wm * 128 + mf * 16 + lq * 4 + i;
                const int s = row & (SEQ - 1);
                const float2 cs0 = cs[s * 32 + lm];
                const float2 cs1 = cs[s * 32 + 16 + lm];
                const float a0 = acc[mf][0][i] + b0, a1 = acc[mf][1][i] + b1;
                const float a2 = acc[mf][2][i] + b2, a3 = acc[mf][3][i] + b3;
                bf16_t* p = C + (size_t)row * DMODEL + cb;
                p[lm]      = (bf16_t)(a0 * cs0.x - a2 * cs0.y);
                p[16 + lm] = (bf16_t)(a1 * cs1.x - a3 * cs1.y);
                p[32 + lm] = (bf16_t)(a2 * cs0.x + a0 * cs0.y);
                p[48 + lm] = (bf16_t)(a3 * cs1.x + a1 * cs1.y);
            }
    } else {      // V epilogue: vt[row=h*64+d][col=b*2048+s], bias per row
#pragma unroll
        for (int mf = 0; mf < 8; ++mf)
#pragma unroll
            for (int i = 0; i < 4; ++i) {
                const int row = m0 + wm * 128 + mf * 16 + lq * 4 + i;
                const float brow = bv[row];
#pragma unroll
                for (int nf = 0; nf < 4; ++nf) {
                    const int col = n0 + wn * 64 + nf * 16 + lm;
                    vtb[(size_t)row * 4096 + col] = (bf16_t)(acc[mf][nf][i] + brow);
                }
            }
    }
}

// ---------------- GEMM core (2-phase 128x128, for output projection) ----------------
template<int NF>
__device__ __forceinline__ void gemm_core(const bf16_t* __restrict__ A,
                                          const bf16_t* __restrict__ Bt,
                                          int m0, int n0,
                                          bf16_t* As, bf16_t* Bs,
                                          f32x4 (&acc)[4][NF]) {
    const int tid = threadIdx.x, lane = tid & 63, wid = tid >> 6;
    const int wr = wid >> 1, wc = wid & 1;
    const int lm = lane & 15, lq = lane >> 4;
    constexpr int BROWS = NF * 32;
    constexpr int NT = DMODEL / 32;

    const int r_in = lane >> 2;
    const int csw  = (((lane & 3) ^ ((lane >> 3) & 3)) << 3);
    const bf16_t* Ag = A  + (size_t)(m0 + 32 * wid + r_in) * DMODEL + csw;
    const bf16_t* Bg = Bt + (size_t)(n0 + (NF * 8) * wid + r_in) * DMODEL + csw;
    const int cswr = ((lq ^ ((lm >> 1) & 3)) << 4);

    auto stage = [&](int t, int buf) {
        const int k0 = t * 32;
        bf16_t* a = As + buf * (128 * 32) + 32 * wid * 32;
        bf16_t* b = Bs + buf * (BROWS * 32) + (NF * 8) * wid * 32;
        GLOAD16(Ag + k0,               a);
        GLOAD16(Ag + 16 * DMODEL + k0, a + 16 * 32);
        GLOAD16(Bg + k0,               b);
        if constexpr (NF == 4) GLOAD16(Bg + 16 * DMODEL + k0, b + 16 * 32);
    };

    stage(0, 0);
    stage(1, 1);
    int cb = 0;
    for (int t = 0; t < NT; ++t) {
        if (t + 2 < NT) {
            int sb = cb + 2; if (sb >= 3) sb -= 3;
            stage(t + 2, sb);
            if constexpr (NF == 4) asm volatile("s_waitcnt vmcnt(8)" ::: "memory");
            else                   asm volatile("s_waitcnt vmcnt(6)" ::: "memory");
        } else if (t + 1 < NT) {
            if constexpr (NF == 4) asm volatile("s_waitcnt vmcnt(4)" ::: "memory");
            else                   asm volatile("s_waitcnt vmcnt(3)" ::: "memory");
        } else {
            asm volatile("s_waitcnt vmcnt(0)" ::: "memory");
        }
        __builtin_amdgcn_s_barrier();

        const char* pAs = (const char*)(As + cb * (128 * 32));
        const char* pBs = (const char*)(Bs + cb * (BROWS * 32));
        bf16x8 af[4], bfr[NF];
#pragma unroll
        for (int mf = 0; mf < 4; ++mf)
            af[mf] = *reinterpret_cast<const bf16x8*>(pAs + (wr * 64 + mf * 16 + lm) * 64 + cswr);
#pragma unroll
        for (int nf = 0; nf < NF; ++nf)
            bfr[nf] = *reinterpret_cast<const bf16x8*>(pBs + (wc * (NF * 16) + nf * 16 + lm) * 64 + cswr);
#pragma unroll
        for (int mf = 0; mf < 4; ++mf)
#pragma unroll
            for (int nf = 0; nf < NF; ++nf)
                acc[mf][nf] = MFMA16(af[mf], bfr[nf], acc[mf][nf]);

        asm volatile("" ::: "memory");
        __builtin_amdgcn_s_barrier();
        if (++cb == 3) cb = 0;
    }
}

// ---------------- output projection: 128x128 tile, 256 blocks (XCD-swizzled) ----------
__global__ __launch_bounds__(256)
void gemm_out_kernel(const bf16_t* __restrict__ A, const bf16_t* __restrict__ Bt,
                     const float* __restrict__ bias, float* __restrict__ C) {
    __shared__ bf16_t As[3 * 128 * 32];
    __shared__ bf16_t Bs[3 * 128 * 32];
    const int tid = threadIdx.x, lane = tid & 63, wid = tid >> 6;
    const int wr = wid >> 1, wc = wid & 1;
    const int lm = lane & 15, lq = lane >> 4;
    const int orig = blockIdx.x;
    const int id = (orig & 7) * 32 + (orig >> 3);   // bijective XCD swizzle (256 = 8*32)
    const int m0 = (id >> 3) * 128, n0 = (id & 7) * 128;
    f32x4 acc[4][4] = {};
    gemm_core<4>(A, Bt, m0, n0, As, Bs, acc);
#pragma unroll
    for (int nf = 0; nf < 4; ++nf) {
        const int col = n0 + wc * 64 + nf * 16 + lm;
        const float bcol = bias[col];
#pragma unroll
        for (int mf = 0; mf < 4; ++mf)
#pragma unroll
            for (int i = 0; i < 4; ++i) {
                const int row = m0 + wr * 64 + mf * 16 + lq * 4 + i;
                C[(size_t)row * DMODEL + col] = acc[mf][nf][i] + bcol;
            }
    }
}

// ---------------- flash attention: pipelined + convoy-broken wave roles (R11) ----------
__global__ __launch_bounds__(256)
void attn_kernel(const bf16_t* __restrict__ q, const bf16_t* __restrict__ k,
                 const bf16_t* __restrict__ vt, bf16_t* __restrict__ attnout) {
    const int tid = threadIdx.x, lane = tid & 63, wid = tid >> 6;
    const int lm = lane & 15, lq = lane >> 4;
    const int bid = blockIdx.x;
    const int xcd = bid & 7, idx = bid >> 3;
    const int bh = xcd * 4 + (idx & 3), qblk = idx >> 2;
    const int b = bh >> 4, h = bh & 15;
    const int qrow0 = qblk * 128 + wid * 32;
    const float MS = 20.0f;
    constexpr int NT = SEQ / 64;

    __shared__ bf16_t Ks[4][64][64];
    __shared__ bf16_t Vs[4][64][64];

    const bf16_t* qA = q + ((size_t)(b * SEQ + qrow0 + lm) * NHEAD + h) * DK + lq * 8;
    const bf16_t* qB = qA + (size_t)16 * NHEAD * DK;
    bf16x8 aqA0 = *reinterpret_cast<const bf16x8*>(qA);
    bf16x8 aqA1 = *reinterpret_cast<const bf16x8*>(qA + 32);
    bf16x8 aqB0 = *reinterpret_cast<const bf16x8*>(qB);
    bf16x8 aqB1 = *reinterpret_cast<const bf16x8*>(qB + 32);
#pragma unroll
    for (int j = 0; j < 8; ++j) {
        aqA0[j] = (bf16_t)((float)aqA0[j] * 0.18033688f);
        aqA1[j] = (bf16_t)((float)aqA1[j] * 0.18033688f);
        aqB0[j] = (bf16_t)((float)aqB0[j] * 0.18033688f);
        aqB1[j] = (bf16_t)((float)aqB1[j] * 0.18033688f);
    }
    const bf16_t one = (bf16_t)1.0f;
    const bf16x8 ones = { one, one, one, one, one, one, one, one };
    const f32x4 cinit = { -MS, -MS, -MS, -MS };

    const int r0   = 8 * wid + (lane >> 3);
    const int scol = (((lane & 7) ^ (lane >> 3)) << 3);
    const int sig  = ((r0 >> 2) & 3) * 8 + ((r0 >> 4) & 1) * 4 + (r0 & 3);
    const bf16_t* kg = k  + ((size_t)(b * SEQ + sig) * NHEAD + h) * DK + scol;
    const bf16_t* vg = vt + ((size_t)(h * DK + r0)) * 4096 + (size_t)b * SEQ + scol;
    const size_t kstep = (size_t)NHEAD * DK;
    const char* ksb = (const char*)Ks;
    const char* vsb = (const char*)Vs;
    const int c0 = (lq << 4) ^ ((lm & 7) << 4);
    const int rowb = lm * 128;

    f32x4 OA[4] = {}, OB[4] = {};
    f32x4 olA = {}, olB = {};

    auto stageK = [&](int buf, int kb) {
        GLOAD16(kg + (size_t)kb * kstep,        &Ks[buf][8 * wid][0]);
        GLOAD16(kg + (size_t)(kb + 32) * kstep, &Ks[buf][32 + 8 * wid][0]);
    };
    auto stageV = [&](int buf, int kb) {
        GLOAD16(vg + kb,                        &Vs[buf][8 * wid][0]);
        GLOAD16(vg + (size_t)32 * 4096 + kb,    &Vs[buf][32 + 8 * wid][0]);
    };
    auto qk = [&](int buf, f32x4 (&sA)[4], f32x4 (&sB)[4]) {
        const char* kt = ksb + buf * 8192;
        __builtin_amdgcn_s_setprio(1);
#pragma unroll
        for (int t = 0; t < 4; ++t) {
            bf16x8 a0 = *reinterpret_cast<const bf16x8*>(kt + t * 2048 + rowb + c0);
            bf16x8 a1 = *reinterpret_cast<const bf16x8*>(kt + t * 2048 + rowb + (c0 ^ 64));
            f32x4 xA = MFMA16(a0, aqA0, cinit);
            xA = MFMA16(a1, aqA1, xA);
            f32x4 xB = MFMA16(a0, aqB0, cinit);
            xB = MFMA16(a1, aqB1, xB);
            sA[t] = xA; sB[t] = xB;
        }
        __builtin_amdgcn_s_setprio(0);
    };
    auto softmax = [&](const f32x4 (&sA)[4], const f32x4 (&sB)[4],
                       bf16x8& pA0, bf16x8& pA1, bf16x8& pB0, bf16x8& pB1) {
#pragma unroll
        for (int u = 0; u < 2; ++u)
#pragma unroll
            for (int i = 0; i < 4; ++i) {
                pA0[4 * u + i] = (bf16_t)exp2_hw(sA[u][i]);
                pA1[4 * u + i] = (bf16_t)exp2_hw(sA[u + 2][i]);
                pB0[4 * u + i] = (bf16_t)exp2_hw(sB[u][i]);
                pB1[4 * u + i] = (bf16_t)exp2_hw(sB[u + 2][i]);
            }
    };
    auto pv = [&](int buf, const bf16x8& pA0, const bf16x8& pA1,
                  const bf16x8& pB0, const bf16x8& pB1) {
        const char* vtl = vsb + buf * 8192;
        __builtin_amdgcn_s_setprio(1);
#pragma unroll
        for (int nf = 0; nf < 4; ++nf) {
            bf16x8 v0 = *reinterpret_cast<const bf16x8*>(vtl + nf * 2048 + rowb + c0);
            bf16x8 v1 = *reinterpret_cast<const bf16x8*>(vtl + nf * 2048 + rowb + (c0 ^ 64));
            f32x4 oA = OA[nf], oB = OB[nf];
            oA = MFMA16(v0, pA0, oA);
            oA = MFMA16(v1, pA1, oA);
            oB = MFMA16(v0, pB0, oB);
            oB = MFMA16(v1, pB1, oB);
            OA[nf] = oA; OB[nf] = oB;
        }
        olA = MFMA16(ones, pA0, olA);
        olA = MFMA16(ones, pA1, olA);
        olB = MFMA16(ones, pB0, olB);
        olB = MFMA16(ones, pB1, olB);
        __builtin_amdgcn_s_setprio(0);
    };

    stageK(0, 0);  stageV(0, 0);
    stageK(1, 64); stageV(1, 64);
    asm volatile("s_waitcnt vmcnt(2)" ::: "memory");
    __builtin_amdgcn_s_barrier();
    asm volatile("" ::: "memory");
    f32x4 stA[4], stB[4];
    qk(0, stA, stB);

    const bool evenw = (wid & 1) == 0;
    for (int t = 0; t < NT; ++t) {
        const int kb = t * 64;
        f32x4 nA[4], nB[4];
        bf16x8 paA0, paA1, paB0, paB1;

        if (t + 2 < NT) stageK((t + 2) & 3, kb + 128);
        if (evenw) {
            if (t + 1 < NT) qk((t + 1) & 3, nA, nB);
            if (t + 2 < NT) stageV((t + 2) & 3, kb + 128);
            softmax(stA, stB, paA0, paA1, paB0, paB1);
            pv(t & 3, paA0, paA1, paB0, paB1);
        } else {
            softmax(stA, stB, paA0, paA1, paB0, paB1);
            pv(t & 3, paA0, paA1, paB0, paB1);
            if (t + 2 < NT) stageV((t + 2) & 3, kb + 128);
            if (t + 1 < NT) qk((t + 1) & 3, nA, nB);
        }

        if (t + 1 < NT) {
            if (t + 2 < NT) asm volatile("s_waitcnt vmcnt(2)" ::: "memory");
            else            asm volatile("s_waitcnt vmcnt(0)" ::: "memory");
            __builtin_amdgcn_s_barrier();
            asm volatile("" ::: "memory");
#pragma unroll
            for (int i = 0; i < 4; ++i) { stA[i] = nA[i]; stB[i] = nB[i]; }
        }
    }

    const float invA = 1.0f / olA[0];
    const float invB = 1.0f / olB[0];
    bf16_t* obA = attnout + ((size_t)(b * SEQ + qrow0 + lm) * NHEAD + h) * DK;
    bf16_t* obB = obA + (size_t)16 * NHEAD * DK;
#pragma unroll
    for (int nf = 0; nf < 4; ++nf) {
        bf16x4 cA = { (bf16_t)(OA[nf][0] * invA), (bf16_t)(OA[nf][1] * invA),
                      (bf16_t)(OA[nf][2] * invA), (bf16_t)(OA[nf][3] * invA) };
        bf16x4 cB = { (bf16_t)(OB[nf][0] * invB), (bf16_t)(OB[nf][1] * invB),
                      (bf16_t)(OB[nf][2] * invB), (bf16_t)(OB[nf][3] * invB) };
        *reinterpret_cast<bf16x4*>(obA + nf * 16 + lq * 4) = cA;
        *reinterpret_cast<bf16x4*>(obB + nf * 16 + lq * 4) = cB;
    }
}

extern "C" void kernel_launch(void* const* d_in, const int* in_sizes, int n_in,
                              void* d_out, int out_size, void* d_ws, size_t ws_size,
                              hipStream_t stream) {
    const float* x  = (const float*)d_in[0];
    const float* Wq = (const float*)d_in[1];
    const float* bq = (const float*)d_in[2];
    const float* Wk = (const float*)d_in[3];
    const float* bk = (const float*)d_in[4];
    const float* Wv = (const float*)d_in[5];
    const float* bv = (const float*)d_in[6];
    const float* Wo = (const float*)d_in[7];
    const float* bo = (const float*)d_in[8];
    float* out = (float*)d_out;

    char* ws = (char*)d_ws;
    bf16_t* xb  = (bf16_t*)(ws);                       // 8MB (x bf16; reused as attn-out)
    bf16_t* wtq = (bf16_t*)(ws + ((size_t)8  << 20));  // 4 x 2MB transposed weights (q,k,v,o)
    bf16_t* wtv = wtq + (2 << 20);
    bf16_t* wto = wtq + (3 << 20);
    bf16_t* qb  = (bf16_t*)(ws + ((size_t)16 << 20));  // 8MB
    bf16_t* kb  = (bf16_t*)(ws + ((size_t)24 << 20));  // 8MB
    bf16_t* vtb = (bf16_t*)(ws + ((size_t)32 << 20));  // 8MB, [1024][4096]
    float2* csT = (float2*)(ws + ((size_t)40 << 20));  // 512KB
    bf16_t* aob = xb;

    prep_kernel<<<8448, 256, 0, stream>>>(x, xb, Wq, Wk, Wv, Wo, wtq, csT);
    gemm_qkv8_kernel<<<192, 512, 0, stream>>>(xb, wtq, wtv, bq, bk, bv, qb, kb, vtb, csT);
    attn_kernel<<<512, 256, 0, stream>>>(qb, kb, vtb, aob);
    gemm_out_kernel<<<256, 256, 0, stream>>>(aob, wto, bo, out);
}

// Round 14
// 123.765 us; speedup vs baseline: 1.1488x; 1.0575x over previous
//
#include <hip/hip_runtime.h>
#include <hip/hip_bf16.h>
#include <math.h>

typedef __bf16 bf16_t;
typedef bf16_t bf16x4 __attribute__((ext_vector_type(4)));
typedef bf16_t bf16x8 __attribute__((ext_vector_type(8)));
typedef float f32x4 __attribute__((ext_vector_type(4)));

#define SEQ 2048
#define BATCH 2
#define NHEAD 16
#define DK 64
#define DMODEL 1024

#define GLOAD16(gsrc, ldst)                                                        \
    __builtin_amdgcn_global_load_lds(                                              \
        (const __attribute__((address_space(1))) void*)(gsrc),                     \
        (__attribute__((address_space(3))) void*)(ldst), 16, 0, 0)

#define MFMA16(a, b, c) __builtin_amdgcn_mfma_f32_16x16x32_bf16((a), (b), (c), 0, 0, 0)

__device__ __forceinline__ float exp2_hw(float x) {
#if __has_builtin(__builtin_amdgcn_exp2f)
    return __builtin_amdgcn_exp2f(x);
#else
    float r; asm("v_exp_f32 %0, %1" : "=v"(r) : "v"(x)); return r;
#endif
}

// ---------------- fused prep: cvt x -> bf16 | transpose 4x W -> bf16 | rope table ----
__global__ __launch_bounds__(256)
void prep_kernel(const float* __restrict__ x, bf16_t* __restrict__ y,
                 const float* __restrict__ W0, const float* __restrict__ W1,
                 const float* __restrict__ W2, const float* __restrict__ W3,
                 bf16_t* __restrict__ Wt, float2* __restrict__ cs) {
    __shared__ float t[32][33];
    const int id = blockIdx.x, tid = threadIdx.x;
    if (id < 4096) {                               // cvt x (4096 blocks)
        int i = (id * 256 + tid) * 4;
        float4 v = *reinterpret_cast<const float4*>(x + i);
        bf16x4 o = { (bf16_t)v.x, (bf16_t)v.y, (bf16_t)v.z, (bf16_t)v.w };
        *reinterpret_cast<bf16x4*>(y + i) = o;
    } else if (id < 8192) {                        // transpose W (4096 blocks)
        const int id2 = id - 4096;
        const int z = id2 >> 10, rem = id2 & 1023;
        const int n0 = (rem & 31) * 32, k0 = ((rem >> 5) & 31) * 32;
        const int tx = tid & 31, ty = tid >> 5;    // 32 x 8
        const float* W = (z == 0) ? W0 : (z == 1) ? W1 : (z == 2) ? W2 : W3;
        bf16_t* out = Wt + ((size_t)z << 20);
#pragma unroll
        for (int i = 0; i < 32; i += 8)
            t[ty + i][tx] = W[(size_t)(k0 + ty + i) * DMODEL + n0 + tx];
        __syncthreads();
#pragma unroll
        for (int i = 0; i < 32; i += 8)
            out[(size_t)(n0 + ty + i) * DMODEL + k0 + tx] = (bf16_t)t[tx][ty + i];
    } else {                                       // rope table (256 blocks)
        int idx = (id - 8192) * 256 + tid;         // SEQ*32
        int j = idx & 31, s = idx >> 5;
        float inv = powf(10000.0f, -(float)j / 32.0f);
        float ang = (float)s * inv;
        cs[idx] = make_float2(cosf(ang), sinf(ang));
    }
}

// ---------------- GEMM core: 128 x (NF*32) tile, BK=32, 3-deep prefetch ----------------
template<int NF>
__device__ __forceinline__ void gemm_core(const bf16_t* __restrict__ A,
                                          const bf16_t* __restrict__ Bt,
                                          int m0, int n0,
                                          bf16_t* As, bf16_t* Bs,
                                          f32x4 (&acc)[4][NF]) {
    const int tid = threadIdx.x, lane = tid & 63, wid = tid >> 6;
    const int wr = wid >> 1, wc = wid & 1;
    const int lm = lane & 15, lq = lane >> 4;
    constexpr int BROWS = NF * 32;
    constexpr int NT = DMODEL / 32;

    const int r_in = lane >> 2;
    const int csw  = (((lane & 3) ^ ((lane >> 3) & 3)) << 3);
    const bf16_t* Ag = A  + (size_t)(m0 + 32 * wid + r_in) * DMODEL + csw;
    const bf16_t* Bg = Bt + (size_t)(n0 + (NF * 8) * wid + r_in) * DMODEL + csw;
    const int cswr = ((lq ^ ((lm >> 1) & 3)) << 4);

    auto stage = [&](int t, int buf) {
        const int k0 = t * 32;
        bf16_t* a = As + buf * (128 * 32) + 32 * wid * 32;
        bf16_t* b = Bs + buf * (BROWS * 32) + (NF * 8) * wid * 32;
        GLOAD16(Ag + k0,               a);
        GLOAD16(Ag + 16 * DMODEL + k0, a + 16 * 32);
        GLOAD16(Bg + k0,               b);
        if constexpr (NF == 4) GLOAD16(Bg + 16 * DMODEL + k0, b + 16 * 32);
    };

    stage(0, 0);
    stage(1, 1);
    int cb = 0;
    for (int t = 0; t < NT; ++t) {
        if (t + 2 < NT) {
            int sb = cb + 2; if (sb >= 3) sb -= 3;
            stage(t + 2, sb);
            if constexpr (NF == 4) asm volatile("s_waitcnt vmcnt(8)" ::: "memory");
            else                   asm volatile("s_waitcnt vmcnt(6)" ::: "memory");
        } else if (t + 1 < NT) {
            if constexpr (NF == 4) asm volatile("s_waitcnt vmcnt(4)" ::: "memory");
            else                   asm volatile("s_waitcnt vmcnt(3)" ::: "memory");
        } else {
            asm volatile("s_waitcnt vmcnt(0)" ::: "memory");
        }
        __builtin_amdgcn_s_barrier();

        const char* pAs = (const char*)(As + cb * (128 * 32));
        const char* pBs = (const char*)(Bs + cb * (BROWS * 32));
        bf16x8 af[4], bfr[NF];
#pragma unroll
        for (int mf = 0; mf < 4; ++mf)
            af[mf] = *reinterpret_cast<const bf16x8*>(pAs + (wr * 64 + mf * 16 + lm) * 64 + cswr);
#pragma unroll
        for (int nf = 0; nf < NF; ++nf)
            bfr[nf] = *reinterpret_cast<const bf16x8*>(pBs + (wc * (NF * 16) + nf * 16 + lm) * 64 + cswr);
#pragma unroll
        for (int mf = 0; mf < 4; ++mf)
#pragma unroll
            for (int nf = 0; nf < NF; ++nf)
                acc[mf][nf] = MFMA16(af[mf], bfr[nf], acc[mf][nf]);

        asm volatile("" ::: "memory");
        __builtin_amdgcn_s_barrier();
        if (++cb == 3) cb = 0;
    }
}

// ---------------- fused QKV projections: 768 blocks (XCD-swizzled) ----------------
__global__ __launch_bounds__(256)
void gemm_qkv_kernel(const bf16_t* __restrict__ xb, const bf16_t* __restrict__ wtqk,
                     const bf16_t* __restrict__ wtv,
                     const float* __restrict__ bq, const float* __restrict__ bk,
                     const float* __restrict__ bv,
                     bf16_t* __restrict__ qb, bf16_t* __restrict__ kb,
                     bf16_t* __restrict__ vtb, const float2* __restrict__ cs) {
    __shared__ bf16_t As[3 * 128 * 32];
    __shared__ bf16_t Bs[3 * 128 * 32];
    const int tid = threadIdx.x, lane = tid & 63, wid = tid >> 6;
    const int wr = wid >> 1, wc = wid & 1;
    const int lm = lane & 15, lq = lane >> 4;
    const int orig = blockIdx.x;
    const int id = (orig & 7) * 96 + (orig >> 3);   // bijective XCD swizzle (768 = 8*96)
    f32x4 acc[4][4] = {};

    if (id < 512) {
        const int m0 = (id >> 4) * 128, n0 = (id & 15) * 128;
        gemm_core<4>(xb, wtqk, m0, n0, As, Bs, acc);
        const bool is_k = (n0 >= 1024);
        const float* bs = is_k ? bk : bq;
        bf16_t* C = is_k ? kb : qb;
        const int cb = (is_k ? n0 - 1024 : n0) + wc * 64;
        const float b0 = bs[cb + lm],      b1 = bs[cb + 16 + lm];
        const float b2 = bs[cb + 32 + lm], b3 = bs[cb + 48 + lm];
#pragma unroll
        for (int mf = 0; mf < 4; ++mf)
#pragma unroll
            for (int i = 0; i < 4; ++i) {
                const int row = m0 + wr * 64 + mf * 16 + lq * 4 + i;
                const int s = row & (SEQ - 1);
                const float2 cs0 = cs[s * 32 + lm];
                const float2 cs1 = cs[s * 32 + 16 + lm];
                const float a0 = acc[mf][0][i] + b0, a1 = acc[mf][1][i] + b1;
                const float a2 = acc[mf][2][i] + b2, a3 = acc[mf][3][i] + b3;
                bf16_t* p = C + (size_t)row * DMODEL + cb;
                p[lm]      = (bf16_t)(a0 * cs0.x - a2 * cs0.y);
                p[16 + lm] = (bf16_t)(a1 * cs1.x - a3 * cs1.y);
                p[32 + lm] = (bf16_t)(a2 * cs0.x + a0 * cs0.y);
                p[48 + lm] = (bf16_t)(a3 * cs1.x + a1 * cs1.y);
            }
    } else {
        const int id2 = id - 512;
        const int m0 = (id2 & 7) * 128, n0 = (id2 >> 3) * 128;
        gemm_core<4>(wtv, xb, m0, n0, As, Bs, acc);
#pragma unroll
        for (int mf = 0; mf < 4; ++mf)
#pragma unroll
            for (int i = 0; i < 4; ++i) {
                const int row = m0 + wr * 64 + mf * 16 + lq * 4 + i;
                const float brow = bv[row];
#pragma unroll
                for (int nf = 0; nf < 4; ++nf) {
                    const int col = n0 + wc * 64 + nf * 16 + lm;
                    vtb[(size_t)row * 4096 + col] = (bf16_t)(acc[mf][nf][i] + brow);
                }
            }
    }
}

// ---------------- output projection: 128x128 tile, 256 blocks (XCD-swizzled) ----------
__global__ __launch_bounds__(256)
void gemm_out_kernel(const bf16_t* __restrict__ A, const bf16_t* __restrict__ Bt,
                     const float* __restrict__ bias, float* __restrict__ C) {
    __shared__ bf16_t As[3 * 128 * 32];
    __shared__ bf16_t Bs[3 * 128 * 32];
    const int tid = threadIdx.x, lane = tid & 63, wid = tid >> 6;
    const int wr = wid >> 1, wc = wid & 1;
    const int lm = lane & 15, lq = lane >> 4;
    const int orig = blockIdx.x;
    const int id = (orig & 7) * 32 + (orig >> 3);   // bijective XCD swizzle (256 = 8*32)
    const int m0 = (id >> 3) * 128, n0 = (id & 7) * 128;
    f32x4 acc[4][4] = {};
    gemm_core<4>(A, Bt, m0, n0, As, Bs, acc);
#pragma unroll
    for (int nf = 0; nf < 4; ++nf) {
        const int col = n0 + wc * 64 + nf * 16 + lm;
        const float bcol = bias[col];
#pragma unroll
        for (int mf = 0; mf < 4; ++mf)
#pragma unroll
            for (int i = 0; i < 4; ++i) {
                const int row = m0 + wr * 64 + mf * 16 + lq * 4 + i;
                C[(size_t)row * DMODEL + col] = acc[mf][nf][i] + bcol;
            }
    }
}

// ---------------- flash attention: KVBLK=128, convoy-break, in-register P --------------
// 4 waves x 32 q-rows (A/B sets). 2 LDS buffers of 128 KV rows (K[128][64], V[64][128]);
// half the barriers/vmcnt-drains per row vs KVBLK=64. sigma row permutation per 64-row
// half (verified: sigma(u*16+4lq+i) = 8lq+4u+i) keeps P in registers in PV B-frag
// order. ones-MFMA denominator; static max in acc-init; even/odd wave convoy-break.
__global__ __launch_bounds__(256)
void attn_kernel(const bf16_t* __restrict__ q, const bf16_t* __restrict__ k,
                 const bf16_t* __restrict__ vt, bf16_t* __restrict__ attnout) {
    const int tid = threadIdx.x, lane = tid & 63, wid = tid >> 6;
    const int lm = lane & 15, lq = lane >> 4;
    const int bid = blockIdx.x;
    const int xcd = bid & 7, idx = bid >> 3;
    const int bh = xcd * 4 + (idx & 3), qblk = idx >> 2;
    const int b = bh >> 4, h = bh & 15;
    const int qrow0 = qblk * 128 + wid * 32;
    const float MS = 20.0f;
    constexpr int NT = SEQ / 128;     // 16 KV tiles of 128

    __shared__ bf16_t Ks[2][128][64];   // 32KB: K rows (sigma-permuted per 64-half)
    __shared__ bf16_t Vs[2][64][128];   // 32KB: V rows = d, 128 kv cols

    const bf16_t* qA = q + ((size_t)(b * SEQ + qrow0 + lm) * NHEAD + h) * DK + lq * 8;
    const bf16_t* qB = qA + (size_t)16 * NHEAD * DK;
    bf16x8 aqA0 = *reinterpret_cast<const bf16x8*>(qA);
    bf16x8 aqA1 = *reinterpret_cast<const bf16x8*>(qA + 32);
    bf16x8 aqB0 = *reinterpret_cast<const bf16x8*>(qB);
    bf16x8 aqB1 = *reinterpret_cast<const bf16x8*>(qB + 32);
#pragma unroll
    for (int j = 0; j < 8; ++j) {
        aqA0[j] = (bf16_t)((float)aqA0[j] * 0.18033688f);
        aqA1[j] = (bf16_t)((float)aqA1[j] * 0.18033688f);
        aqB0[j] = (bf16_t)((float)aqB0[j] * 0.18033688f);
        aqB1[j] = (bf16_t)((float)aqB1[j] * 0.18033688f);
    }
    const bf16_t one = (bf16_t)1.0f;
    const bf16x8 ones = { one, one, one, one, one, one, one, one };
    const f32x4 cinit = { -MS, -MS, -MS, -MS };

    // K staging: 4 chunks of 8 LDS rows; row = 32*wid + 8*c + rr
    const int rr = lane >> 3;
    const int scolK = (((lane & 7) ^ rr) << 3);
    const size_t kstep = (size_t)NHEAD * DK;
    const bf16_t* kgc[4];
#pragma unroll
    for (int c = 0; c < 4; ++c) {
        const int row = 32 * wid + 8 * c + rr;
        const int half = row >> 6, r6 = row & 63;
        const int sigr = (r6 & 32) | (((r6 >> 2) & 3) << 3) | (((r6 >> 4) & 1) << 2) | (r6 & 3);
        kgc[c] = k + ((size_t)(b * SEQ + half * 64 + sigr) * NHEAD + h) * DK + scolK;
    }
    // V staging: 4 chunks of 4 LDS rows (256B each); row d = 16*wid + 4*c + (lane>>4)
    const bf16_t* vgc[4];
#pragma unroll
    for (int c = 0; c < 4; ++c) {
        const int d = 16 * wid + 4 * c + (lane >> 4);
        const int g = lane & 15, half128 = g >> 3, gin = g & 7;
        const int colsrc = half128 * 64 + ((gin ^ (d & 7)) << 3);
        vgc[c] = vt + ((size_t)(h * DK + d)) * 4096 + (size_t)b * SEQ + colsrc;
    }

    const char* ksb = (const char*)Ks;
    const char* vsb = (const char*)Vs;
    const int c0 = (lq << 4) ^ ((lm & 7) << 4);
    const int rowbK = lm * 128;

    f32x4 OA[4] = {}, OB[4] = {};
    f32x4 olA = {}, olB = {};

    auto stage = [&](int buf, int kb) {
#pragma unroll
        for (int c = 0; c < 4; ++c) {
            GLOAD16(kgc[c] + (size_t)kb * kstep, &Ks[buf][32 * wid + 8 * c][0]);
            GLOAD16(vgc[c] + kb,                 &Vs[buf][16 * wid + 4 * c][0]);
        }
    };
    auto qk = [&](int buf, int sub, f32x4 (&sA)[4], f32x4 (&sB)[4]) {
        const char* kt = ksb + buf * 16384 + sub * 8192;
        __builtin_amdgcn_s_setprio(1);
#pragma unroll
        for (int t = 0; t < 4; ++t) {
            bf16x8 a0 = *reinterpret_cast<const bf16x8*>(kt + t * 2048 + rowbK + c0);
            bf16x8 a1 = *reinterpret_cast<const bf16x8*>(kt + t * 2048 + rowbK + (c0 ^ 64));
            f32x4 xA = MFMA16(a0, aqA0, cinit);
            xA = MFMA16(a1, aqA1, xA);
            f32x4 xB = MFMA16(a0, aqB0, cinit);
            xB = MFMA16(a1, aqB1, xB);
            sA[t] = xA; sB[t] = xB;
        }
        __builtin_amdgcn_s_setprio(0);
    };
    auto softmax = [&](const f32x4 (&sA)[4], const f32x4 (&sB)[4],
                       bf16x8& pA0, bf16x8& pA1, bf16x8& pB0, bf16x8& pB1) {
#pragma unroll
        for (int u = 0; u < 2; ++u)
#pragma unroll
            for (int i = 0; i < 4; ++i) {
                pA0[4 * u + i] = (bf16_t)exp2_hw(sA[u][i]);
                pA1[4 * u + i] = (bf16_t)exp2_hw(sA[u + 2][i]);
                pB0[4 * u + i] = (bf16_t)exp2_hw(sB[u][i]);
                pB1[4 * u + i] = (bf16_t)exp2_hw(sB[u + 2][i]);
            }
    };
    auto pv = [&](int buf, int sub, const bf16x8& pA0, const bf16x8& pA1,
                  const bf16x8& pB0, const bf16x8& pB1) {
        const char* vtl = vsb + buf * 16384;
        __builtin_amdgcn_s_setprio(1);
#pragma unroll
        for (int nf = 0; nf < 4; ++nf) {
            const char* vr = vtl + nf * 4096 + lm * 256 + sub * 128;
            bf16x8 v0 = *reinterpret_cast<const bf16x8*>(vr + c0);
            bf16x8 v1 = *reinterpret_cast<const bf16x8*>(vr + (c0 ^ 64));
            f32x4 oA = OA[nf], oB = OB[nf];
            oA = MFMA16(v0, pA0, oA);
            oA = MFMA16(v1, pA1, oA);
            oB = MFMA16(v0, pB0, oB);
            oB = MFMA16(v1, pB1, oB);
            OA[nf] = oA; OB[nf] = oB;
        }
        olA = MFMA16(ones, pA0, olA);
        olA = MFMA16(ones, pA1, olA);
        olB = MFMA16(ones, pB0, olB);
        olB = MFMA16(ones, pB1, olB);
        __builtin_amdgcn_s_setprio(0);
    };

    // prologue: stage tiles 0,1 (8+8 loads); vmcnt(8) -> tile0 landed
    stage(0, 0);
    stage(1, 128);
    asm volatile("s_waitcnt vmcnt(8)" ::: "memory");
    __builtin_amdgcn_s_barrier();
    asm volatile("" ::: "memory");

    f32x4 stA[4], stB[4];
    qk(0, 0, stA, stB);

    const bool evenw = (wid & 1) == 0;
    for (int t = 0; t < NT; ++t) {
        const int buf = t & 1;
        f32x4 nA[4], nB[4];
        bf16x8 paA0, paA1, paB0, paB1;

        // sub 0: QK(t,1) overlapped with softmax/PV(t,0), convoy-ordered
        if (evenw) {
            qk(buf, 1, nA, nB);
            softmax(stA, stB, paA0, paA1, paB0, paB1);
            pv(buf, 0, paA0, paA1, paB0, paB1);
        } else {
            softmax(stA, stB, paA0, paA1, paB0, paB1);
            pv(buf, 0, paA0, paA1, paB0, paB1);
            qk(buf, 1, nA, nB);
        }
        // sub 1
        softmax(nA, nB, paA0, paA1, paB0, paB1);
        pv(buf, 1, paA0, paA1, paB0, paB1);

        if (t + 1 < NT) {
            asm volatile("" ::: "memory");
            __builtin_amdgcn_s_barrier();            // tile t reads complete
            if (t + 2 < NT) {
                stage(buf, (t + 2) * 128);           // overwrite tile t's buffer
                asm volatile("s_waitcnt vmcnt(8)" ::: "memory");  // tile t+1 landed
            } else {
                asm volatile("s_waitcnt vmcnt(0)" ::: "memory");
            }
            __builtin_amdgcn_s_barrier();            // tile t+1 visible to all waves
            asm volatile("" ::: "memory");
            qk((t + 1) & 1, 0, stA, stB);
        }
    }

    const float invA = 1.0f / olA[0];
    const float invB = 1.0f / olB[0];
    bf16_t* obA = attnout + ((size_t)(b * SEQ + qrow0 + lm) * NHEAD + h) * DK;
    bf16_t* obB = obA + (size_t)16 * NHEAD * DK;
#pragma unroll
    for (int nf = 0; nf < 4; ++nf) {
        bf16x4 cA = { (bf16_t)(OA[nf][0] * invA), (bf16_t)(OA[nf][1] * invA),
                      (bf16_t)(OA[nf][2] * invA), (bf16_t)(OA[nf][3] * invA) };
        bf16x4 cB = { (bf16_t)(OB[nf][0] * invB), (bf16_t)(OB[nf][1] * invB),
                      (bf16_t)(OB[nf][2] * invB), (bf16_t)(OB[nf][3] * invB) };
        *reinterpret_cast<bf16x4*>(obA + nf * 16 + lq * 4) = cA;
        *reinterpret_cast<bf16x4*>(obB + nf * 16 + lq * 4) = cB;
    }
}

extern "C" void kernel_launch(void* const* d_in, const int* in_sizes, int n_in,
                              void* d_out, int out_size, void* d_ws, size_t ws_size,
                              hipStream_t stream) {
    const float* x  = (const float*)d_in[0];
    const float* Wq = (const float*)d_in[1];
    const float* bq = (const float*)d_in[2];
    const float* Wk = (const float*)d_in[3];
    const float* bk = (const float*)d_in[4];
    const float* Wv = (const float*)d_in[5];
    const float* bv = (const float*)d_in[6];
    const float* Wo = (const float*)d_in[7];
    const float* bo = (const float*)d_in[8];
    float* out = (float*)d_out;

    char* ws = (char*)d_ws;
    bf16_t* xb  = (bf16_t*)(ws);                       // 8MB (x bf16; reused as attn-out)
    bf16_t* wtq = (bf16_t*)(ws + ((size_t)8  << 20));  // 4 x 2MB transposed weights (q,k,v,o)
    bf16_t* wtv = wtq + (2 << 20);
    bf16_t* wto = wtq + (3 << 20);
    bf16_t* qb  = (bf16_t*)(ws + ((size_t)16 << 20));  // 8MB
    bf16_t* kb  = (bf16_t*)(ws + ((size_t)24 << 20));  // 8MB
    bf16_t* vtb = (bf16_t*)(ws + ((size_t)32 << 20));  // 8MB, [1024][4096]
    float2* csT = (float2*)(ws + ((size_t)40 << 20));  // 512KB
    bf16_t* aob = xb;

    prep_kernel<<<8448, 256, 0, stream>>>(x, xb, Wq, Wk, Wv, Wo, wtq, csT);
    gemm_qkv_kernel<<<768, 256, 0, stream>>>(xb, wtq, wtv, bq, bk, bv, qb, kb, vtb, csT);
    attn_kernel<<<512, 256, 0, stream>>>(qb, kb, vtb, aob);
    gemm_out_kernel<<<256, 256, 0, stream>>>(aob, wto, bo, out);
}

// Round 15
// 113.491 us; speedup vs baseline: 1.2528x; 1.0905x over previous
//
#include <hip/hip_runtime.h>
#include <hip/hip_bf16.h>
#include <math.h>

typedef __bf16 bf16_t;
typedef bf16_t bf16x4 __attribute__((ext_vector_type(4)));
typedef bf16_t bf16x8 __attribute__((ext_vector_type(8)));
typedef float f32x4 __attribute__((ext_vector_type(4)));

#define SEQ 2048
#define BATCH 2
#define NHEAD 16
#define DK 64
#define DMODEL 1024

#define GLOAD16(gsrc, ldst)                                                        \
    __builtin_amdgcn_global_load_lds(                                              \
        (const __attribute__((address_space(1))) void*)(gsrc),                     \
        (__attribute__((address_space(3))) void*)(ldst), 16, 0, 0)

#define MFMA16(a, b, c) __builtin_amdgcn_mfma_f32_16x16x32_bf16((a), (b), (c), 0, 0, 0)

__device__ __forceinline__ float exp2_hw(float x) {
#if __has_builtin(__builtin_amdgcn_exp2f)
    return __builtin_amdgcn_exp2f(x);
#else
    float r; asm("v_exp_f32 %0, %1" : "=v"(r) : "v"(x)); return r;
#endif
}

// ---------------- fused prep: cvt x -> bf16 | transpose 4x W -> bf16 | rope table ----
__global__ __launch_bounds__(256)
void prep_kernel(const float* __restrict__ x, bf16_t* __restrict__ y,
                 const float* __restrict__ W0, const float* __restrict__ W1,
                 const float* __restrict__ W2, const float* __restrict__ W3,
                 bf16_t* __restrict__ Wt, float2* __restrict__ cs) {
    __shared__ float t[32][33];
    const int id = blockIdx.x, tid = threadIdx.x;
    if (id < 4096) {                               // cvt x (4096 blocks)
        int i = (id * 256 + tid) * 4;
        float4 v = *reinterpret_cast<const float4*>(x + i);
        bf16x4 o = { (bf16_t)v.x, (bf16_t)v.y, (bf16_t)v.z, (bf16_t)v.w };
        *reinterpret_cast<bf16x4*>(y + i) = o;
    } else if (id < 8192) {                        // transpose W (4096 blocks)
        const int id2 = id - 4096;
        const int z = id2 >> 10, rem = id2 & 1023;
        const int n0 = (rem & 31) * 32, k0 = ((rem >> 5) & 31) * 32;
        const int tx = tid & 31, ty = tid >> 5;    // 32 x 8
        const float* W = (z == 0) ? W0 : (z == 1) ? W1 : (z == 2) ? W2 : W3;
        bf16_t* out = Wt + ((size_t)z << 20);
#pragma unroll
        for (int i = 0; i < 32; i += 8)
            t[ty + i][tx] = W[(size_t)(k0 + ty + i) * DMODEL + n0 + tx];
        __syncthreads();
#pragma unroll
        for (int i = 0; i < 32; i += 8)
            out[(size_t)(n0 + ty + i) * DMODEL + k0 + tx] = (bf16_t)t[tx][ty + i];
    } else {                                       // rope table (256 blocks)
        int idx = (id - 8192) * 256 + tid;         // SEQ*32
        int j = idx & 31, s = idx >> 5;
        float inv = powf(10000.0f, -(float)j / 32.0f);
        float ang = (float)s * inv;
        cs[idx] = make_float2(cosf(ang), sinf(ang));
    }
}

// ---------------- GEMM core: 128 x (NF*32) tile, BK=32, 2-buf 1-ahead ----------------
// 2 buffers (A 16KB + B 8/16KB) -> 5-6 blocks/CU: block-level TLP hides stage stalls
// (m97/m114 mechanism). stage(t+1) -> counted vmcnt (tile t landed, t+1 in flight) ->
// barrier -> compute(t) -> barrier. Both-sides XOR swizzle (rule #21).
template<int NF>
__device__ __forceinline__ void gemm_core(const bf16_t* __restrict__ A,
                                          const bf16_t* __restrict__ Bt,
                                          int m0, int n0,
                                          bf16_t* As, bf16_t* Bs,
                                          f32x4 (&acc)[4][NF]) {
    const int tid = threadIdx.x, lane = tid & 63, wid = tid >> 6;
    const int wr = wid >> 1, wc = wid & 1;
    const int lm = lane & 15, lq = lane >> 4;
    constexpr int BROWS = NF * 32;
    constexpr int NT = DMODEL / 32;

    const int r_in = lane >> 2;
    const int csw  = (((lane & 3) ^ ((lane >> 3) & 3)) << 3);
    const bf16_t* Ag = A  + (size_t)(m0 + 32 * wid + r_in) * DMODEL + csw;
    const bf16_t* Bg = Bt + (size_t)(n0 + (NF * 8) * wid + r_in) * DMODEL + csw;
    const int cswr = ((lq ^ ((lm >> 1) & 3)) << 4);

    auto stage = [&](int t, int buf) {
        const int k0 = t * 32;
        bf16_t* a = As + buf * (128 * 32) + 32 * wid * 32;
        bf16_t* b = Bs + buf * (BROWS * 32) + (NF * 8) * wid * 32;
        GLOAD16(Ag + k0,               a);
        GLOAD16(Ag + 16 * DMODEL + k0, a + 16 * 32);
        GLOAD16(Bg + k0,               b);
        if constexpr (NF == 4) GLOAD16(Bg + 16 * DMODEL + k0, b + 16 * 32);
    };

    stage(0, 0);
    for (int t = 0; t < NT; ++t) {
        if (t + 1 < NT) {
            stage(t + 1, (t + 1) & 1);
            if constexpr (NF == 4) asm volatile("s_waitcnt vmcnt(4)" ::: "memory");
            else                   asm volatile("s_waitcnt vmcnt(3)" ::: "memory");
        } else {
            asm volatile("s_waitcnt vmcnt(0)" ::: "memory");
        }
        __builtin_amdgcn_s_barrier();

        const char* pAs = (const char*)(As + (t & 1) * (128 * 32));
        const char* pBs = (const char*)(Bs + (t & 1) * (BROWS * 32));
        bf16x8 af[4], bfr[NF];
#pragma unroll
        for (int mf = 0; mf < 4; ++mf)
            af[mf] = *reinterpret_cast<const bf16x8*>(pAs + (wr * 64 + mf * 16 + lm) * 64 + cswr);
#pragma unroll
        for (int nf = 0; nf < NF; ++nf)
            bfr[nf] = *reinterpret_cast<const bf16x8*>(pBs + (wc * (NF * 16) + nf * 16 + lm) * 64 + cswr);
#pragma unroll
        for (int mf = 0; mf < 4; ++mf)
#pragma unroll
            for (int nf = 0; nf < NF; ++nf)
                acc[mf][nf] = MFMA16(af[mf], bfr[nf], acc[mf][nf]);

        asm volatile("" ::: "memory");
        __builtin_amdgcn_s_barrier();
    }
}

// ---------------- fused QKV projections: 768 blocks (XCD-swizzled) ----------------
__global__ __launch_bounds__(256)
void gemm_qkv_kernel(const bf16_t* __restrict__ xb, const bf16_t* __restrict__ wtqk,
                     const bf16_t* __restrict__ wtv,
                     const float* __restrict__ bq, const float* __restrict__ bk,
                     const float* __restrict__ bv,
                     bf16_t* __restrict__ qb, bf16_t* __restrict__ kb,
                     bf16_t* __restrict__ vtb, const float2* __restrict__ cs) {
    __shared__ bf16_t As[2 * 128 * 32];
    __shared__ bf16_t Bs[2 * 128 * 32];
    const int tid = threadIdx.x, lane = tid & 63, wid = tid >> 6;
    const int wr = wid >> 1, wc = wid & 1;
    const int lm = lane & 15, lq = lane >> 4;
    const int orig = blockIdx.x;
    const int id = (orig & 7) * 96 + (orig >> 3);   // bijective XCD swizzle (768 = 8*96)
    f32x4 acc[4][4] = {};

    if (id < 512) {
        const int m0 = (id >> 4) * 128, n0 = (id & 15) * 128;
        gemm_core<4>(xb, wtqk, m0, n0, As, Bs, acc);
        const bool is_k = (n0 >= 1024);
        const float* bs = is_k ? bk : bq;
        bf16_t* C = is_k ? kb : qb;
        const int cb = (is_k ? n0 - 1024 : n0) + wc * 64;
        const float b0 = bs[cb + lm],      b1 = bs[cb + 16 + lm];
        const float b2 = bs[cb + 32 + lm], b3 = bs[cb + 48 + lm];
#pragma unroll
        for (int mf = 0; mf < 4; ++mf)
#pragma unroll
            for (int i = 0; i < 4; ++i) {
                const int row = m0 + wr * 64 + mf * 16 + lq * 4 + i;
                const int s = row & (SEQ - 1);
                const float2 cs0 = cs[s * 32 + lm];
                const float2 cs1 = cs[s * 32 + 16 + lm];
                const float a0 = acc[mf][0][i] + b0, a1 = acc[mf][1][i] + b1;
                const float a2 = acc[mf][2][i] + b2, a3 = acc[mf][3][i] + b3;
                bf16_t* p = C + (size_t)row * DMODEL + cb;
                p[lm]      = (bf16_t)(a0 * cs0.x - a2 * cs0.y);
                p[16 + lm] = (bf16_t)(a1 * cs1.x - a3 * cs1.y);
                p[32 + lm] = (bf16_t)(a2 * cs0.x + a0 * cs0.y);
                p[48 + lm] = (bf16_t)(a3 * cs1.x + a1 * cs1.y);
            }
    } else {
        const int id2 = id - 512;
        const int m0 = (id2 & 7) * 128, n0 = (id2 >> 3) * 128;
        gemm_core<4>(wtv, xb, m0, n0, As, Bs, acc);
#pragma unroll
        for (int mf = 0; mf < 4; ++mf)
#pragma unroll
            for (int i = 0; i < 4; ++i) {
                const int row = m0 + wr * 64 + mf * 16 + lq * 4 + i;
                const float brow = bv[row];
#pragma unroll
                for (int nf = 0; nf < 4; ++nf) {
                    const int col = n0 + wc * 64 + nf * 16 + lm;
                    vtb[(size_t)row * 4096 + col] = (bf16_t)(acc[mf][nf][i] + brow);
                }
            }
    }
}

// ---------------- output projection: 128x64 tile, 512 blocks (XCD-swizzled) ----------
__global__ __launch_bounds__(256)
void gemm_out_kernel(const bf16_t* __restrict__ A, const bf16_t* __restrict__ Bt,
                     const float* __restrict__ bias, float* __restrict__ C) {
    __shared__ bf16_t As[2 * 128 * 32];
    __shared__ bf16_t Bs[2 * 64 * 32];
    const int tid = threadIdx.x, lane = tid & 63, wid = tid >> 6;
    const int wr = wid >> 1, wc = wid & 1;
    const int lm = lane & 15, lq = lane >> 4;
    const int orig = blockIdx.x;
    const int id = (orig & 7) * 64 + (orig >> 3);   // bijective XCD swizzle (512 = 8*64)
    const int m0 = (id >> 4) * 128, n0 = (id & 15) * 64;
    f32x4 acc[4][2] = {};
    gemm_core<2>(A, Bt, m0, n0, As, Bs, acc);
#pragma unroll
    for (int nf = 0; nf < 2; ++nf) {
        const int col = n0 + wc * 32 + nf * 16 + lm;
        const float bcol = bias[col];
#pragma unroll
        for (int mf = 0; mf < 4; ++mf)
#pragma unroll
            for (int i = 0; i < 4; ++i) {
                const int row = m0 + wr * 64 + mf * 16 + lq * 4 + i;
                C[(size_t)row * DMODEL + col] = acc[mf][nf][i] + bcol;
            }
    }
}

// ---------------- flash attention: pipelined + convoy-broken wave roles (R11 best) ----
// 4 waves x 32 q-rows, in-register P (sigma-permuted K staging), ones-MFMA denom,
// static max in acc-init. 4 LDS buffers, 1 barrier/iter with counted vmcnt(2):
// even waves: [stageK | QK(t+1) | stageV | softmax(t) | PV(t)]
// odd  waves: [stageK | softmax(t) | PV(t) | stageV | QK(t+1)]
// XCD-grouped block decode: each XCD owns 4 heads -> K/V working set 2MB fits its L2.
__global__ __launch_bounds__(256)
void attn_kernel(const bf16_t* __restrict__ q, const bf16_t* __restrict__ k,
                 const bf16_t* __restrict__ vt, bf16_t* __restrict__ attnout) {
    const int tid = threadIdx.x, lane = tid & 63, wid = tid >> 6;
    const int lm = lane & 15, lq = lane >> 4;
    const int bid = blockIdx.x;
    const int xcd = bid & 7, idx = bid >> 3;
    const int bh = xcd * 4 + (idx & 3), qblk = idx >> 2;
    const int b = bh >> 4, h = bh & 15;
    const int qrow0 = qblk * 128 + wid * 32;
    const float MS = 20.0f;
    constexpr int NT = SEQ / 64;

    __shared__ bf16_t Ks[4][64][64];
    __shared__ bf16_t Vs[4][64][64];

    const bf16_t* qA = q + ((size_t)(b * SEQ + qrow0 + lm) * NHEAD + h) * DK + lq * 8;
    const bf16_t* qB = qA + (size_t)16 * NHEAD * DK;
    bf16x8 aqA0 = *reinterpret_cast<const bf16x8*>(qA);
    bf16x8 aqA1 = *reinterpret_cast<const bf16x8*>(qA + 32);
    bf16x8 aqB0 = *reinterpret_cast<const bf16x8*>(qB);
    bf16x8 aqB1 = *reinterpret_cast<const bf16x8*>(qB + 32);
#pragma unroll
    for (int j = 0; j < 8; ++j) {
        aqA0[j] = (bf16_t)((float)aqA0[j] * 0.18033688f);
        aqA1[j] = (bf16_t)((float)aqA1[j] * 0.18033688f);
        aqB0[j] = (bf16_t)((float)aqB0[j] * 0.18033688f);
        aqB1[j] = (bf16_t)((float)aqB1[j] * 0.18033688f);
    }
    const bf16_t one = (bf16_t)1.0f;
    const bf16x8 ones = { one, one, one, one, one, one, one, one };
    const f32x4 cinit = { -MS, -MS, -MS, -MS };

    const int r0   = 8 * wid + (lane >> 3);
    const int scol = (((lane & 7) ^ (lane >> 3)) << 3);
    const int sig  = ((r0 >> 2) & 3) * 8 + ((r0 >> 4) & 1) * 4 + (r0 & 3);
    const bf16_t* kg = k  + ((size_t)(b * SEQ + sig) * NHEAD + h) * DK + scol;
    const bf16_t* vg = vt + ((size_t)(h * DK + r0)) * 4096 + (size_t)b * SEQ + scol;
    const size_t kstep = (size_t)NHEAD * DK;
    const char* ksb = (const char*)Ks;
    const char* vsb = (const char*)Vs;
    const int c0 = (lq << 4) ^ ((lm & 7) << 4);
    const int rowb = lm * 128;

    f32x4 OA[4] = {}, OB[4] = {};
    f32x4 olA = {}, olB = {};

    auto stageK = [&](int buf, int kb) {
        GLOAD16(kg + (size_t)kb * kstep,        &Ks[buf][8 * wid][0]);
        GLOAD16(kg + (size_t)(kb + 32) * kstep, &Ks[buf][32 + 8 * wid][0]);
    };
    auto stageV = [&](int buf, int kb) {
        GLOAD16(vg + kb,                        &Vs[buf][8 * wid][0]);
        GLOAD16(vg + (size_t)32 * 4096 + kb,    &Vs[buf][32 + 8 * wid][0]);
    };
    auto qk = [&](int buf, f32x4 (&sA)[4], f32x4 (&sB)[4]) {
        const char* kt = ksb + buf * 8192;
        __builtin_amdgcn_s_setprio(1);
#pragma unroll
        for (int t = 0; t < 4; ++t) {
            bf16x8 a0 = *reinterpret_cast<const bf16x8*>(kt + t * 2048 + rowb + c0);
            bf16x8 a1 = *reinterpret_cast<const bf16x8*>(kt + t * 2048 + rowb + (c0 ^ 64));
            f32x4 xA = MFMA16(a0, aqA0, cinit);
            xA = MFMA16(a1, aqA1, xA);
            f32x4 xB = MFMA16(a0, aqB0, cinit);
            xB = MFMA16(a1, aqB1, xB);
            sA[t] = xA; sB[t] = xB;
        }
        __builtin_amdgcn_s_setprio(0);
    };
    auto softmax = [&](const f32x4 (&sA)[4], const f32x4 (&sB)[4],
                       bf16x8& pA0, bf16x8& pA1, bf16x8& pB0, bf16x8& pB1) {
#pragma unroll
        for (int u = 0; u < 2; ++u)
#pragma unroll
            for (int i = 0; i < 4; ++i) {
                pA0[4 * u + i] = (bf16_t)exp2_hw(sA[u][i]);
                pA1[4 * u + i] = (bf16_t)exp2_hw(sA[u + 2][i]);
                pB0[4 * u + i] = (bf16_t)exp2_hw(sB[u][i]);
                pB1[4 * u + i] = (bf16_t)exp2_hw(sB[u + 2][i]);
            }
    };
    auto pv = [&](int buf, const bf16x8& pA0, const bf16x8& pA1,
                  const bf16x8& pB0, const bf16x8& pB1) {
        const char* vtl = vsb + buf * 8192;
        __builtin_amdgcn_s_setprio(1);
#pragma unroll
        for (int nf = 0; nf < 4; ++nf) {
            bf16x8 v0 = *reinterpret_cast<const bf16x8*>(vtl + nf * 2048 + rowb + c0);
            bf16x8 v1 = *reinterpret_cast<const bf16x8*>(vtl + nf * 2048 + rowb + (c0 ^ 64));
            f32x4 oA = OA[nf], oB = OB[nf];
            oA = MFMA16(v0, pA0, oA);
            oA = MFMA16(v1, pA1, oA);
            oB = MFMA16(v0, pB0, oB);
            oB = MFMA16(v1, pB1, oB);
            OA[nf] = oA; OB[nf] = oB;
        }
        olA = MFMA16(ones, pA0, olA);
        olA = MFMA16(ones, pA1, olA);
        olB = MFMA16(ones, pB0, olB);
        olB = MFMA16(ones, pB1, olB);
        __builtin_amdgcn_s_setprio(0);
    };

    stageK(0, 0);  stageV(0, 0);
    stageK(1, 64); stageV(1, 64);
    asm volatile("s_waitcnt vmcnt(2)" ::: "memory");
    __builtin_amdgcn_s_barrier();
    asm volatile("" ::: "memory");
    f32x4 stA[4], stB[4];
    qk(0, stA, stB);

    const bool evenw = (wid & 1) == 0;
    for (int t = 0; t < NT; ++t) {
        const int kb = t * 64;
        f32x4 nA[4], nB[4];
        bf16x8 paA0, paA1, paB0, paB1;

        if (t + 2 < NT) stageK((t + 2) & 3, kb + 128);
        if (evenw) {
            if (t + 1 < NT) qk((t + 1) & 3, nA, nB);
            if (t + 2 < NT) stageV((t + 2) & 3, kb + 128);
            softmax(stA, stB, paA0, paA1, paB0, paB1);
            pv(t & 3, paA0, paA1, paB0, paB1);
        } else {
            softmax(stA, stB, paA0, paA1, paB0, paB1);
            pv(t & 3, paA0, paA1, paB0, paB1);
            if (t + 2 < NT) stageV((t + 2) & 3, kb + 128);
            if (t + 1 < NT) qk((t + 1) & 3, nA, nB);
        }

        if (t + 1 < NT) {
            if (t + 2 < NT) asm volatile("s_waitcnt vmcnt(2)" ::: "memory");
            else            asm volatile("s_waitcnt vmcnt(0)" ::: "memory");
            __builtin_amdgcn_s_barrier();
            asm volatile("" ::: "memory");
#pragma unroll
            for (int i = 0; i < 4; ++i) { stA[i] = nA[i]; stB[i] = nB[i]; }
        }
    }

    const float invA = 1.0f / olA[0];
    const float invB = 1.0f / olB[0];
    bf16_t* obA = attnout + ((size_t)(b * SEQ + qrow0 + lm) * NHEAD + h) * DK;
    bf16_t* obB = obA + (size_t)16 * NHEAD * DK;
#pragma unroll
    for (int nf = 0; nf < 4; ++nf) {
        bf16x4 cA = { (bf16_t)(OA[nf][0] * invA), (bf16_t)(OA[nf][1] * invA),
                      (bf16_t)(OA[nf][2] * invA), (bf16_t)(OA[nf][3] * invA) };
        bf16x4 cB = { (bf16_t)(OB[nf][0] * invB), (bf16_t)(OB[nf][1] * invB),
                      (bf16_t)(OB[nf][2] * invB), (bf16_t)(OB[nf][3] * invB) };
        *reinterpret_cast<bf16x4*>(obA + nf * 16 + lq * 4) = cA;
        *reinterpret_cast<bf16x4*>(obB + nf * 16 + lq * 4) = cB;
    }
}

extern "C" void kernel_launch(void* const* d_in, const int* in_sizes, int n_in,
                              void* d_out, int out_size, void* d_ws, size_t ws_size,
                              hipStream_t stream) {
    const float* x  = (const float*)d_in[0];
    const float* Wq = (const float*)d_in[1];
    const float* bq = (const float*)d_in[2];
    const float* Wk = (const float*)d_in[3];
    const float* bk = (const float*)d_in[4];
    const float* Wv = (const float*)d_in[5];
    const float* bv = (const float*)d_in[6];
    const float* Wo = (const float*)d_in[7];
    const float* bo = (const float*)d_in[8];
    float* out = (float*)d_out;

    char* ws = (char*)d_ws;
    bf16_t* xb  = (bf16_t*)(ws);                       // 8MB (x bf16; reused as attn-out)
    bf16_t* wtq = (bf16_t*)(ws + ((size_t)8  << 20));  // 4 x 2MB transposed weights (q,k,v,o)
    bf16_t* wtv = wtq + (2 << 20);
    bf16_t* wto = wtq + (3 << 20);
    bf16_t* qb  = (bf16_t*)(ws + ((size_t)16 << 20));  // 8MB
    bf16_t* kb  = (bf16_t*)(ws + ((size_t)24 << 20));  // 8MB
    bf16_t* vtb = (bf16_t*)(ws + ((size_t)32 << 20));  // 8MB, [1024][4096]
    float2* csT = (float2*)(ws + ((size_t)40 << 20));  // 512KB
    bf16_t* aob = xb;

    prep_kernel<<<8448, 256, 0, stream>>>(x, xb, Wq, Wk, Wv, Wo, wtq, csT);
    gemm_qkv_kernel<<<768, 256, 0, stream>>>(xb, wtq, wtv, bq, bk, bv, qb, kb, vtb, csT);
    attn_kernel<<<512, 256, 0, stream>>>(qb, kb, vtb, aob);
    gemm_out_kernel<<<512, 256, 0, stream>>>(aob, wto, bo, out);
}

// Round 16
// 113.032 us; speedup vs baseline: 1.2579x; 1.0041x over previous
//
#include <hip/hip_runtime.h>
#include <hip/hip_bf16.h>
#include <math.h>

typedef __bf16 bf16_t;
typedef bf16_t bf16x4 __attribute__((ext_vector_type(4)));
typedef bf16_t bf16x8 __attribute__((ext_vector_type(8)));
typedef float f32x4 __attribute__((ext_vector_type(4)));

#define SEQ 2048
#define BATCH 2
#define NHEAD 16
#define DK 64
#define DMODEL 1024

#define GLOAD16(gsrc, ldst)                                                        \
    __builtin_amdgcn_global_load_lds(                                              \
        (const __attribute__((address_space(1))) void*)(gsrc),                     \
        (__attribute__((address_space(3))) void*)(ldst), 16, 0, 0)

#define MFMA16(a, b, c) __builtin_amdgcn_mfma_f32_16x16x32_bf16((a), (b), (c), 0, 0, 0)

__device__ __forceinline__ float exp2_hw(float x) {
#if __has_builtin(__builtin_amdgcn_exp2f)
    return __builtin_amdgcn_exp2f(x);
#else
    float r; asm("v_exp_f32 %0, %1" : "=v"(r) : "v"(x)); return r;
#endif
}

// ---------------- fused prep: cvt x -> bf16 | transpose 4x W -> bf16 | rope table ----
__global__ __launch_bounds__(256)
void prep_kernel(const float* __restrict__ x, bf16_t* __restrict__ y,
                 const float* __restrict__ W0, const float* __restrict__ W1,
                 const float* __restrict__ W2, const float* __restrict__ W3,
                 bf16_t* __restrict__ Wt, float2* __restrict__ cs) {
    __shared__ float t[32][33];
    const int id = blockIdx.x, tid = threadIdx.x;
    if (id < 4096) {                               // cvt x (4096 blocks)
        int i = (id * 256 + tid) * 4;
        float4 v = *reinterpret_cast<const float4*>(x + i);
        bf16x4 o = { (bf16_t)v.x, (bf16_t)v.y, (bf16_t)v.z, (bf16_t)v.w };
        *reinterpret_cast<bf16x4*>(y + i) = o;
    } else if (id < 8192) {                        // transpose W (4096 blocks)
        const int id2 = id - 4096;
        const int z = id2 >> 10, rem = id2 & 1023;
        const int n0 = (rem & 31) * 32, k0 = ((rem >> 5) & 31) * 32;
        const int tx = tid & 31, ty = tid >> 5;    // 32 x 8
        const float* W = (z == 0) ? W0 : (z == 1) ? W1 : (z == 2) ? W2 : W3;
        bf16_t* out = Wt + ((size_t)z << 20);
#pragma unroll
        for (int i = 0; i < 32; i += 8)
            t[ty + i][tx] = W[(size_t)(k0 + ty + i) * DMODEL + n0 + tx];
        __syncthreads();
#pragma unroll
        for (int i = 0; i < 32; i += 8)
            out[(size_t)(n0 + ty + i) * DMODEL + k0 + tx] = (bf16_t)t[tx][ty + i];
    } else {                                       // rope table (256 blocks)
        int idx = (id - 8192) * 256 + tid;         // SEQ*32
        int j = idx & 31, s = idx >> 5;
        float inv = powf(10000.0f, -(float)j / 32.0f);
        float ang = (float)s * inv;
        cs[idx] = make_float2(cosf(ang), sinf(ang));
    }
}

// ---------------- GEMM core: 128 x (NF*32) tile, BK=32, 2-buf 1-ahead ----------------
// 2 buffers -> 5-6 blocks/CU: block-level TLP hides stage stalls (m97/m114 mechanism).
template<int NF>
__device__ __forceinline__ void gemm_core(const bf16_t* __restrict__ A,
                                          const bf16_t* __restrict__ Bt,
                                          int m0, int n0,
                                          bf16_t* As, bf16_t* Bs,
                                          f32x4 (&acc)[4][NF]) {
    const int tid = threadIdx.x, lane = tid & 63, wid = tid >> 6;
    const int wr = wid >> 1, wc = wid & 1;
    const int lm = lane & 15, lq = lane >> 4;
    constexpr int BROWS = NF * 32;
    constexpr int NT = DMODEL / 32;

    const int r_in = lane >> 2;
    const int csw  = (((lane & 3) ^ ((lane >> 3) & 3)) << 3);
    const bf16_t* Ag = A  + (size_t)(m0 + 32 * wid + r_in) * DMODEL + csw;
    const bf16_t* Bg = Bt + (size_t)(n0 + (NF * 8) * wid + r_in) * DMODEL + csw;
    const int cswr = ((lq ^ ((lm >> 1) & 3)) << 4);

    auto stage = [&](int t, int buf) {
        const int k0 = t * 32;
        bf16_t* a = As + buf * (128 * 32) + 32 * wid * 32;
        bf16_t* b = Bs + buf * (BROWS * 32) + (NF * 8) * wid * 32;
        GLOAD16(Ag + k0,               a);
        GLOAD16(Ag + 16 * DMODEL + k0, a + 16 * 32);
        GLOAD16(Bg + k0,               b);
        if constexpr (NF == 4) GLOAD16(Bg + 16 * DMODEL + k0, b + 16 * 32);
    };

    stage(0, 0);
    for (int t = 0; t < NT; ++t) {
        if (t + 1 < NT) {
            stage(t + 1, (t + 1) & 1);
            if constexpr (NF == 4) asm volatile("s_waitcnt vmcnt(4)" ::: "memory");
            else                   asm volatile("s_waitcnt vmcnt(3)" ::: "memory");
        } else {
            asm volatile("s_waitcnt vmcnt(0)" ::: "memory");
        }
        __builtin_amdgcn_s_barrier();

        const char* pAs = (const char*)(As + (t & 1) * (128 * 32));
        const char* pBs = (const char*)(Bs + (t & 1) * (BROWS * 32));
        bf16x8 af[4], bfr[NF];
#pragma unroll
        for (int mf = 0; mf < 4; ++mf)
            af[mf] = *reinterpret_cast<const bf16x8*>(pAs + (wr * 64 + mf * 16 + lm) * 64 + cswr);
#pragma unroll
        for (int nf = 0; nf < NF; ++nf)
            bfr[nf] = *reinterpret_cast<const bf16x8*>(pBs + (wc * (NF * 16) + nf * 16 + lm) * 64 + cswr);
#pragma unroll
        for (int mf = 0; mf < 4; ++mf)
#pragma unroll
            for (int nf = 0; nf < NF; ++nf)
                acc[mf][nf] = MFMA16(af[mf], bfr[nf], acc[mf][nf]);

        asm volatile("" ::: "memory");
        __builtin_amdgcn_s_barrier();
    }
}

// ---------------- fused QKV projections: 768 blocks (XCD-swizzled) ----------------
__global__ __launch_bounds__(256)
void gemm_qkv_kernel(const bf16_t* __restrict__ xb, const bf16_t* __restrict__ wtqk,
                     const bf16_t* __restrict__ wtv,
                     const float* __restrict__ bq, const float* __restrict__ bk,
                     const float* __restrict__ bv,
                     bf16_t* __restrict__ qb, bf16_t* __restrict__ kb,
                     bf16_t* __restrict__ vtb, const float2* __restrict__ cs) {
    __shared__ bf16_t As[2 * 128 * 32];
    __shared__ bf16_t Bs[2 * 128 * 32];
    const int tid = threadIdx.x, lane = tid & 63, wid = tid >> 6;
    const int wr = wid >> 1, wc = wid & 1;
    const int lm = lane & 15, lq = lane >> 4;
    const int orig = blockIdx.x;
    const int id = (orig & 7) * 96 + (orig >> 3);   // bijective XCD swizzle (768 = 8*96)
    f32x4 acc[4][4] = {};

    if (id < 512) {
        const int m0 = (id >> 4) * 128, n0 = (id & 15) * 128;
        gemm_core<4>(xb, wtqk, m0, n0, As, Bs, acc);
        const bool is_k = (n0 >= 1024);
        const float* bs = is_k ? bk : bq;
        bf16_t* C = is_k ? kb : qb;
        const int cb = (is_k ? n0 - 1024 : n0) + wc * 64;
        const float b0 = bs[cb + lm],      b1 = bs[cb + 16 + lm];
        const float b2 = bs[cb + 32 + lm], b3 = bs[cb + 48 + lm];
#pragma unroll
        for (int mf = 0; mf < 4; ++mf)
#pragma unroll
            for (int i = 0; i < 4; ++i) {
                const int row = m0 + wr * 64 + mf * 16 + lq * 4 + i;
                const int s = row & (SEQ - 1);
                const float2 cs0 = cs[s * 32 + lm];
                const float2 cs1 = cs[s * 32 + 16 + lm];
                const float a0 = acc[mf][0][i] + b0, a1 = acc[mf][1][i] + b1;
                const float a2 = acc[mf][2][i] + b2, a3 = acc[mf][3][i] + b3;
                bf16_t* p = C + (size_t)row * DMODEL + cb;
                p[lm]      = (bf16_t)(a0 * cs0.x - a2 * cs0.y);
                p[16 + lm] = (bf16_t)(a1 * cs1.x - a3 * cs1.y);
                p[32 + lm] = (bf16_t)(a2 * cs0.x + a0 * cs0.y);
                p[48 + lm] = (bf16_t)(a3 * cs1.x + a1 * cs1.y);
            }
    } else {
        const int id2 = id - 512;
        const int m0 = (id2 & 7) * 128, n0 = (id2 >> 3) * 128;
        gemm_core<4>(wtv, xb, m0, n0, As, Bs, acc);
#pragma unroll
        for (int mf = 0; mf < 4; ++mf)
#pragma unroll
            for (int i = 0; i < 4; ++i) {
                const int row = m0 + wr * 64 + mf * 16 + lq * 4 + i;
                const float brow = bv[row];
#pragma unroll
                for (int nf = 0; nf < 4; ++nf) {
                    const int col = n0 + wc * 64 + nf * 16 + lm;
                    vtb[(size_t)row * 4096 + col] = (bf16_t)(acc[mf][nf][i] + brow);
                }
            }
    }
}

// ---------------- output projection: 128x64 tile, 512 blocks (XCD-swizzled) ----------
__global__ __launch_bounds__(256)
void gemm_out_kernel(const bf16_t* __restrict__ A, const bf16_t* __restrict__ Bt,
                     const float* __restrict__ bias, float* __restrict__ C) {
    __shared__ bf16_t As[2 * 128 * 32];
    __shared__ bf16_t Bs[2 * 64 * 32];
    const int tid = threadIdx.x, lane = tid & 63, wid = tid >> 6;
    const int wr = wid >> 1, wc = wid & 1;
    const int lm = lane & 15, lq = lane >> 4;
    const int orig = blockIdx.x;
    const int id = (orig & 7) * 64 + (orig >> 3);   // bijective XCD swizzle (512 = 8*64)
    const int m0 = (id >> 4) * 128, n0 = (id & 15) * 64;
    f32x4 acc[4][2] = {};
    gemm_core<2>(A, Bt, m0, n0, As, Bs, acc);
#pragma unroll
    for (int nf = 0; nf < 2; ++nf) {
        const int col = n0 + wc * 32 + nf * 16 + lm;
        const float bcol = bias[col];
#pragma unroll
        for (int mf = 0; mf < 4; ++mf)
#pragma unroll
            for (int i = 0; i < 4; ++i) {
                const int row = m0 + wr * 64 + mf * 16 + lq * 4 + i;
                C[(size_t)row * DMODEL + col] = acc[mf][nf][i] + bcol;
            }
    }
}

// ---------------- flash attention: R11 pipeline, 3 LDS buffers (48KB -> 3 blocks/CU) --
// 4 waves x 32 q-rows, in-register P (sigma-permuted K staging), ones-MFMA denom,
// static max in acc-init. Exactly 3 live tiles: PV reads V[t], QK reads K[t+1],
// stage writes t+2 -> 3 buffers suffice; 12 waves/CU (+50% TLP vs 4-buf).
// even waves: [stageK | QK(t+1) | stageV | softmax(t) | PV(t)]
// odd  waves: [stageK | softmax(t) | PV(t) | stageV | QK(t+1)]
__global__ __launch_bounds__(256)
void attn_kernel(const bf16_t* __restrict__ q, const bf16_t* __restrict__ k,
                 const bf16_t* __restrict__ vt, bf16_t* __restrict__ attnout) {
    const int tid = threadIdx.x, lane = tid & 63, wid = tid >> 6;
    const int lm = lane & 15, lq = lane >> 4;
    const int bid = blockIdx.x;
    const int xcd = bid & 7, idx = bid >> 3;
    const int bh = xcd * 4 + (idx & 3), qblk = idx >> 2;
    const int b = bh >> 4, h = bh & 15;
    const int qrow0 = qblk * 128 + wid * 32;
    const float MS = 20.0f;
    constexpr int NT = SEQ / 64;

    __shared__ bf16_t Ks[3][64][64];
    __shared__ bf16_t Vs[3][64][64];

    const bf16_t* qA = q + ((size_t)(b * SEQ + qrow0 + lm) * NHEAD + h) * DK + lq * 8;
    const bf16_t* qB = qA + (size_t)16 * NHEAD * DK;
    bf16x8 aqA0 = *reinterpret_cast<const bf16x8*>(qA);
    bf16x8 aqA1 = *reinterpret_cast<const bf16x8*>(qA + 32);
    bf16x8 aqB0 = *reinterpret_cast<const bf16x8*>(qB);
    bf16x8 aqB1 = *reinterpret_cast<const bf16x8*>(qB + 32);
#pragma unroll
    for (int j = 0; j < 8; ++j) {
        aqA0[j] = (bf16_t)((float)aqA0[j] * 0.18033688f);
        aqA1[j] = (bf16_t)((float)aqA1[j] * 0.18033688f);
        aqB0[j] = (bf16_t)((float)aqB0[j] * 0.18033688f);
        aqB1[j] = (bf16_t)((float)aqB1[j] * 0.18033688f);
    }
    const bf16_t one = (bf16_t)1.0f;
    const bf16x8 ones = { one, one, one, one, one, one, one, one };
    const f32x4 cinit = { -MS, -MS, -MS, -MS };

    const int r0   = 8 * wid + (lane >> 3);
    const int scol = (((lane & 7) ^ (lane >> 3)) << 3);
    const int sig  = ((r0 >> 2) & 3) * 8 + ((r0 >> 4) & 1) * 4 + (r0 & 3);
    const bf16_t* kg = k  + ((size_t)(b * SEQ + sig) * NHEAD + h) * DK + scol;
    const bf16_t* vg = vt + ((size_t)(h * DK + r0)) * 4096 + (size_t)b * SEQ + scol;
    const size_t kstep = (size_t)NHEAD * DK;
    const char* ksb = (const char*)Ks;
    const char* vsb = (const char*)Vs;
    const int c0 = (lq << 4) ^ ((lm & 7) << 4);
    const int rowb = lm * 128;

    f32x4 OA[4] = {}, OB[4] = {};
    f32x4 olA = {}, olB = {};

    auto stageK = [&](int buf, int kb) {
        GLOAD16(kg + (size_t)kb * kstep,        &Ks[buf][8 * wid][0]);
        GLOAD16(kg + (size_t)(kb + 32) * kstep, &Ks[buf][32 + 8 * wid][0]);
    };
    auto stageV = [&](int buf, int kb) {
        GLOAD16(vg + kb,                        &Vs[buf][8 * wid][0]);
        GLOAD16(vg + (size_t)32 * 4096 + kb,    &Vs[buf][32 + 8 * wid][0]);
    };
    auto qk = [&](int buf, f32x4 (&sA)[4], f32x4 (&sB)[4]) {
        const char* kt = ksb + buf * 8192;
        __builtin_amdgcn_s_setprio(1);
#pragma unroll
        for (int t = 0; t < 4; ++t) {
            bf16x8 a0 = *reinterpret_cast<const bf16x8*>(kt + t * 2048 + rowb + c0);
            bf16x8 a1 = *reinterpret_cast<const bf16x8*>(kt + t * 2048 + rowb + (c0 ^ 64));
            f32x4 xA = MFMA16(a0, aqA0, cinit);
            xA = MFMA16(a1, aqA1, xA);
            f32x4 xB = MFMA16(a0, aqB0, cinit);
            xB = MFMA16(a1, aqB1, xB);
            sA[t] = xA; sB[t] = xB;
        }
        __builtin_amdgcn_s_setprio(0);
    };
    auto softmax = [&](const f32x4 (&sA)[4], const f32x4 (&sB)[4],
                       bf16x8& pA0, bf16x8& pA1, bf16x8& pB0, bf16x8& pB1) {
#pragma unroll
        for (int u = 0; u < 2; ++u)
#pragma unroll
            for (int i = 0; i < 4; ++i) {
                pA0[4 * u + i] = (bf16_t)exp2_hw(sA[u][i]);
                pA1[4 * u + i] = (bf16_t)exp2_hw(sA[u + 2][i]);
                pB0[4 * u + i] = (bf16_t)exp2_hw(sB[u][i]);
                pB1[4 * u + i] = (bf16_t)exp2_hw(sB[u + 2][i]);
            }
    };
    auto pv = [&](int buf, const bf16x8& pA0, const bf16x8& pA1,
                  const bf16x8& pB0, const bf16x8& pB1) {
        const char* vtl = vsb + buf * 8192;
        __builtin_amdgcn_s_setprio(1);
#pragma unroll
        for (int nf = 0; nf < 4; ++nf) {
            bf16x8 v0 = *reinterpret_cast<const bf16x8*>(vtl + nf * 2048 + rowb + c0);
            bf16x8 v1 = *reinterpret_cast<const bf16x8*>(vtl + nf * 2048 + rowb + (c0 ^ 64));
            f32x4 oA = OA[nf], oB = OB[nf];
            oA = MFMA16(v0, pA0, oA);
            oA = MFMA16(v1, pA1, oA);
            oB = MFMA16(v0, pB0, oB);
            oB = MFMA16(v1, pB1, oB);
            OA[nf] = oA; OB[nf] = oB;
        }
        olA = MFMA16(ones, pA0, olA);
        olA = MFMA16(ones, pA1, olA);
        olB = MFMA16(ones, pB0, olB);
        olB = MFMA16(ones, pB1, olB);
        __builtin_amdgcn_s_setprio(0);
    };

    // prologue: stage tiles 0,1 into bufs 0,1; vmcnt(4) -> tile 0 landed
    stageK(0, 0);  stageV(0, 0);
    stageK(1, 64); stageV(1, 64);
    asm volatile("s_waitcnt vmcnt(4)" ::: "memory");
    __builtin_amdgcn_s_barrier();
    asm volatile("" ::: "memory");
    f32x4 stA[4], stB[4];
    qk(0, stA, stB);

    const bool evenw = (wid & 1) == 0;
    int bc = 0, bn = 1, bs = 2;   // buffers holding tiles t, t+1, t+2
    for (int t = 0; t < NT; ++t) {
        const int kb = t * 64;
        f32x4 nA[4], nB[4];
        bf16x8 paA0, paA1, paB0, paB1;

        if (t + 2 < NT) stageK(bs, kb + 128);
        if (evenw) {
            if (t + 1 < NT) qk(bn, nA, nB);
            if (t + 2 < NT) stageV(bs, kb + 128);
            softmax(stA, stB, paA0, paA1, paB0, paB1);
            pv(bc, paA0, paA1, paB0, paB1);
        } else {
            softmax(stA, stB, paA0, paA1, paB0, paB1);
            pv(bc, paA0, paA1, paB0, paB1);
            if (t + 2 < NT) stageV(bs, kb + 128);
            if (t + 1 < NT) qk(bn, nA, nB);
        }

        if (t + 1 < NT) {
            if (t + 2 < NT) asm volatile("s_waitcnt vmcnt(4)" ::: "memory");
            else            asm volatile("s_waitcnt vmcnt(0)" ::: "memory");
            __builtin_amdgcn_s_barrier();
            asm volatile("" ::: "memory");
#pragma unroll
            for (int i = 0; i < 4; ++i) { stA[i] = nA[i]; stB[i] = nB[i]; }
            const int tmp = bc; bc = bn; bn = bs; bs = tmp;   // rotate buffers
        }
    }

    const float invA = 1.0f / olA[0];
    const float invB = 1.0f / olB[0];
    bf16_t* obA = attnout + ((size_t)(b * SEQ + qrow0 + lm) * NHEAD + h) * DK;
    bf16_t* obB = obA + (size_t)16 * NHEAD * DK;
#pragma unroll
    for (int nf = 0; nf < 4; ++nf) {
        bf16x4 cA = { (bf16_t)(OA[nf][0] * invA), (bf16_t)(OA[nf][1] * invA),
                      (bf16_t)(OA[nf][2] * invA), (bf16_t)(OA[nf][3] * invA) };
        bf16x4 cB = { (bf16_t)(OB[nf][0] * invB), (bf16_t)(OB[nf][1] * invB),
                      (bf16_t)(OB[nf][2] * invB), (bf16_t)(OB[nf][3] * invB) };
        *reinterpret_cast<bf16x4*>(obA + nf * 16 + lq * 4) = cA;
        *reinterpret_cast<bf16x4*>(obB + nf * 16 + lq * 4) = cB;
    }
}

extern "C" void kernel_launch(void* const* d_in, const int* in_sizes, int n_in,
                              void* d_out, int out_size, void* d_ws, size_t ws_size,
                              hipStream_t stream) {
    const float* x  = (const float*)d_in[0];
    const float* Wq = (const float*)d_in[1];
    const float* bq = (const float*)d_in[2];
    const float* Wk = (const float*)d_in[3];
    const float* bk = (const float*)d_in[4];
    const float* Wv = (const float*)d_in[5];
    const float* bv = (const float*)d_in[6];
    const float* Wo = (const float*)d_in[7];
    const float* bo = (const float*)d_in[8];
    float* out = (float*)d_out;

    char* ws = (char*)d_ws;
    bf16_t* xb  = (bf16_t*)(ws);                       // 8MB (x bf16; reused as attn-out)
    bf16_t* wtq = (bf16_t*)(ws + ((size_t)8  << 20));  // 4 x 2MB transposed weights (q,k,v,o)
    bf16_t* wtv = wtq + (2 << 20);
    bf16_t* wto = wtq + (3 << 20);
    bf16_t* qb  = (bf16_t*)(ws + ((size_t)16 << 20));  // 8MB
    bf16_t* kb  = (bf16_t*)(ws + ((size_t)24 << 20));  // 8MB
    bf16_t* vtb = (bf16_t*)(ws + ((size_t)32 << 20));  // 8MB, [1024][4096]
    float2* csT = (float2*)(ws + ((size_t)40 << 20));  // 512KB
    bf16_t* aob = xb;

    prep_kernel<<<8448, 256, 0, stream>>>(x, xb, Wq, Wk, Wv, Wo, wtq, csT);
    gemm_qkv_kernel<<<768, 256, 0, stream>>>(xb, wtq, wtv, bq, bk, bv, qb, kb, vtb, csT);
    attn_kernel<<<512, 256, 0, stream>>>(qb, kb, vtb, aob);
    gemm_out_kernel<<<512, 256, 0, stream>>>(aob, wto, bo, out);
}